// Round 10
// baseline (593.573 us; speedup 1.0000x reference)
//
#include <hip/hip_runtime.h>
#include <hip/hip_bf16.h>
#include <math.h>

// Problem constants (AydinConfig: H=1024, I=2048, E=8, K=2; B=4, S=2048)
#define NEXP 8
#define HD 1024
#define ID 2048
#define NTOK 8192          // B*S
#define NROWS 16384        // NTOK * top_k

typedef __bf16 bf16_t;
typedef __bf16 bf16x8 __attribute__((ext_vector_type(8)));
typedef float f32x4 __attribute__((ext_vector_type(4)));

// MEASURED LEDGER (do not regress):
//  r1 (4-wave 256thr) 601us; r5 atomicAdd epi +21; r6 gemm2 BN=64 +22
//    -> gemm2 = BN=128 + ybuf + combine.
//  r7 launch_bounds cap < need -> SPILL (WRITE 65->355MB). Never cap below need.
//  r8 8-wave/512thr: occ 31->60%, dur FLAT -> occupancy not binding; LDS pipe is
//    (64KB/block-K-step ~= measured 191us).
//  r9 involution swizzle both-sides: conflicts 2.6e7 -> 0, gemm1 192us,
//    total 591us (best). Conflict cycles were mostly overlapped; VOLUME is king.
//  => r10: gemm1 256-row tile, wave=64rows: 0.5 ds_read/MFMA (was 0.75),
//     LDS traffic/work 64->44KB (1.45x). acc 64 + ~55 CSV fits 128 granule.
//     gemm2 unchanged from r9 (single-variable).
#define BK 32
#define MAXT1 72           // 256-row tiles: sum ceil(c/256) <= 71
#define MAXT2 136          // 128-row tiles: sum ceil(c/128) <= 135

// async global->LDS, 16B per lane. LDS dest must be wave-uniform base + lane*16.
__device__ __forceinline__ void gl16(const void* g, void* l) {
    __builtin_amdgcn_global_load_lds(
        (const __attribute__((address_space(1))) unsigned int*)g,
        (__attribute__((address_space(3))) unsigned int*)l, 16, 0, 0);
}

// ---------------------------------------------------------------- router ----
__global__ __launch_bounds__(256)
void router_kernel(const float* __restrict__ x, const float* __restrict__ rw,
                   bf16_t* __restrict__ xb, int* __restrict__ topk_idx,
                   float* __restrict__ topk_w)
{
    const int t = blockIdx.x;
    const int tid = threadIdx.x;
    const float4 xv = ((const float4*)(x + (size_t)t * HD))[tid];
    float acc[NEXP];
#pragma unroll
    for (int e = 0; e < NEXP; ++e) {
        const float4 w4 = ((const float4*)(rw + e * HD))[tid];
        acc[e] = xv.x * w4.x + xv.y * w4.y + xv.z * w4.z + xv.w * w4.w;
    }
    bf16_t tmp[4] = {(bf16_t)xv.x, (bf16_t)xv.y, (bf16_t)xv.z, (bf16_t)xv.w};
    *(uint2*)(xb + (size_t)t * HD + tid * 4) = *(const uint2*)tmp;

    __shared__ float red[4][NEXP];
    const int lane = tid & 63, wv = tid >> 6;
#pragma unroll
    for (int e = 0; e < NEXP; ++e) {
        float v = acc[e];
#pragma unroll
        for (int off = 32; off >= 1; off >>= 1) v += __shfl_down(v, off, 64);
        if (lane == 0) red[wv][e] = v;
    }
    __syncthreads();
    if (tid == 0) {
        float lg[NEXP], mx = -1e30f;
#pragma unroll
        for (int e = 0; e < NEXP; ++e) {
            lg[e] = red[0][e] + red[1][e] + red[2][e] + red[3][e];
            mx = fmaxf(mx, lg[e]);
        }
        float p[NEXP], s = 0.f;
#pragma unroll
        for (int e = 0; e < NEXP; ++e) { p[e] = __expf(lg[e] - mx); s += p[e]; }
        const float inv = 1.f / s;
#pragma unroll
        for (int e = 0; e < NEXP; ++e) p[e] *= inv;
        int i0 = 0; float p0 = p[0];
#pragma unroll
        for (int e = 1; e < NEXP; ++e) if (p[e] > p0) { p0 = p[e]; i0 = e; }
        int i1 = -1; float p1 = -1.f;
#pragma unroll
        for (int e = 0; e < NEXP; ++e) if (e != i0 && p[e] > p1) { p1 = p[e]; i1 = e; }
        const float d = 1.f / (p0 + p1 + 1e-6f);
        topk_idx[t * 2 + 0] = i0; topk_idx[t * 2 + 1] = i1;
        topk_w[t * 2 + 0] = p0 * d; topk_w[t * 2 + 1] = p1 * d;
    }
}

// ----------------------------------------------------------------- count ----
__global__ __launch_bounds__(256)
void count_kernel(const int* __restrict__ topk_idx, int* __restrict__ counts)
{
    __shared__ int lc[NEXP];
    const int tid = threadIdx.x;
    if (tid < NEXP) lc[tid] = 0;
    __syncthreads();
    const int t = blockIdx.x * 256 + tid;
    atomicAdd(&lc[topk_idx[t * 2 + 0]], 1);
    atomicAdd(&lc[topk_idx[t * 2 + 1]], 1);
    __syncthreads();
    if (tid < NEXP) atomicAdd(&counts[tid], lc[tid]);
}

// ------------------------------------------------------------------ scan ----
// offsets/cursor prefix + BOTH tile maps (256-row for gemm1, 128-row for gemm2)
__global__ void scan_kernel(const int* __restrict__ counts, int* __restrict__ offsets,
                            int* __restrict__ cursor,
                            unsigned* __restrict__ map256, unsigned* __restrict__ map128)
{
    __shared__ int tb2[NEXP + 1], tb1[NEXP + 1];
    if (threadIdx.x == 0) {
        int s = 0, t2 = 0, t1 = 0;
        for (int e = 0; e < NEXP; ++e) {
            offsets[e] = s; cursor[e] = s; s += counts[e];
            tb2[e] = t2; t2 += (counts[e] + 255) >> 8;
            tb1[e] = t1; t1 += (counts[e] + 127) >> 7;
        }
        tb2[NEXP] = t2; tb1[NEXP] = t1;
    }
    __syncthreads();
    for (int i = threadIdx.x; i < MAXT1; i += 64) {
        unsigned v = 0xFFFFFFFFu;
#pragma unroll
        for (int e = 0; e < NEXP; ++e)
            if (i >= tb2[e] && i < tb2[e + 1]) v = ((unsigned)e << 16) | (unsigned)(i - tb2[e]);
        map256[i] = v;
    }
    for (int i = threadIdx.x; i < MAXT2; i += 64) {
        unsigned v = 0xFFFFFFFFu;
#pragma unroll
        for (int e = 0; e < NEXP; ++e)
            if (i >= tb1[e] && i < tb1[e + 1]) v = ((unsigned)e << 16) | (unsigned)(i - tb1[e]);
        map128[i] = v;
    }
}

// --------------------------------------------------------------- scatter ----
__global__ __launch_bounds__(256)
void scatter_kernel(const int* __restrict__ topk_idx, const float* __restrict__ topk_w,
                    int* __restrict__ cursor, int* __restrict__ token_list,
                    float* __restrict__ row_w, int* __restrict__ row_pos)
{
    __shared__ int lc[NEXP], gbase[NEXP];
    const int tid = threadIdx.x;
    if (tid < NEXP) lc[tid] = 0;
    __syncthreads();
    const int t = blockIdx.x * 256 + tid;
    const int e0 = topk_idx[t * 2 + 0], e1 = topk_idx[t * 2 + 1];
    const int lp0 = atomicAdd(&lc[e0], 1);
    const int lp1 = atomicAdd(&lc[e1], 1);
    __syncthreads();
    if (tid < NEXP) gbase[tid] = atomicAdd(&cursor[tid], lc[tid]);
    __syncthreads();
    const int p0 = gbase[e0] + lp0, p1 = gbase[e1] + lp1;
    token_list[p0] = t; row_w[p0] = topk_w[t * 2 + 0]; row_pos[t * 2 + 0] = p0;
    token_list[p1] = t; row_w[p1] = topk_w[t * 2 + 1]; row_pos[t * 2 + 1] = p1;
}

// -------------------------------------------------------- precast weights ----
__global__ __launch_bounds__(256)
void precast_kernel(const float* __restrict__ src, bf16_t* __restrict__ dst,
                    int K, int N)
{
    const int e = blockIdx.z;
    src += (size_t)e * K * N;
    dst += (size_t)e * K * N;
    const int n0 = blockIdx.x * 64, k0 = blockIdx.y * 64;
    __shared__ float tile[64][65];
    const int tid = threadIdx.x;
    const int tx = (tid & 15) * 4, ty = tid >> 4;
#pragma unroll
    for (int p = 0; p < 4; ++p) {
        const float4 v = *(const float4*)(src + (size_t)(k0 + ty + p * 16) * N + n0 + tx);
        tile[ty + p * 16][tx + 0] = v.x;
        tile[ty + p * 16][tx + 1] = v.y;
        tile[ty + p * 16][tx + 2] = v.z;
        tile[ty + p * 16][tx + 3] = v.w;
    }
    __syncthreads();
    const int n = tid >> 2, kc = (tid & 3) * 16;
    bf16_t outv[16];
#pragma unroll
    for (int j = 0; j < 16; ++j) outv[j] = (bf16_t)tile[kc + j][n];
    bf16_t* d = dst + (size_t)(n0 + n) * K + k0 + kc;
    *(uint4*)d = *(uint4*)outv;
    *(uint4*)(d + 8) = *((uint4*)outv + 1);
}

// ------------------------------------------------- grouped GEMM1 + SwiGLU ----
// 256-row x 64-swiglu-col tile, 512 thr / 8 waves. Wave = 64 rows x (32g+32u):
// 8 ds_read_b128 -> 16 MFMA (0.5 reads/MFMA). Involution swizzle (r9, 0-conf):
// logical chunk at (row, phys p) = p ^ ((row>>1)&3) on gl16 SOURCE + read addr.
__global__ __launch_bounds__(512)
void gemm1_kernel(const bf16_t* __restrict__ xb, const bf16_t* __restrict__ w13b,
                  const int* __restrict__ offsets, const int* __restrict__ counts,
                  const int* __restrict__ token_list,
                  const unsigned* __restrict__ tile_map, bf16_t* __restrict__ hbuf)
{
    const unsigned tm = tile_map[blockIdx.y];
    if (tm == 0xFFFFFFFFu) return;
    const int e = (int)(tm >> 16), mt = (int)(tm & 0xFFFFu);
    const int rows = counts[e];
    const int row_base = offsets[e];
    const int r0 = mt * 256;
    const int n0 = blockIdx.x * 64;          // swiglu-col tile (64 gate + 64 up)

    __shared__ alignas(16) bf16_t As[256][32];   // 16 KiB
    __shared__ alignas(16) bf16_t Bg[64][32];    // 4 KiB
    __shared__ alignas(16) bf16_t Bu[64][32];    // 4 KiB

    const int tid = threadIdx.x;
    const int lane = tid & 63;
    const int wv = tid >> 6;                 // 0..7
    const int wr = wv >> 1, wc = wv & 1;     // wave: rows [wr*64,+64), cols [wc*32,+32)
    const int ln15 = lane & 15, q = lane >> 4;
    const int cs = (q ^ ((ln15 >> 1) & 3)) * 8;   // swizzled read chunk

    // staging: A rows tid>>2 and +128 (2 gl16); B split: waves 0-3 gate, 4-7 up.
    const int srowA = tid >> 2;
    const int scolA = ((tid & 3) ^ ((tid >> 3) & 3)) * 8;  // (row>>1)&3 == (tid>>3)&3
    const int tb = tid & 255;
    const int srowB = tb >> 2;
    const int scolB = ((tb & 3) ^ ((tb >> 3) & 3)) * 8;
    int grA0 = row_base + r0 + srowA;       if (grA0 > NROWS - 1) grA0 = NROWS - 1;
    int grA1 = row_base + r0 + 128 + srowA; if (grA1 > NROWS - 1) grA1 = NROWS - 1;
    const bf16_t* a0 = xb + (size_t)token_list[grA0] * HD + scolA;
    const bf16_t* a1 = xb + (size_t)token_list[grA1] * HD + scolA;
    const bf16_t* wb = w13b + (size_t)e * HD * (2 * ID);
    const bf16_t* b0 = wb + (size_t)((tid < 256 ? 0 : ID) + n0 + srowB) * HD + scolB;
    bf16_t* const d_a0 = &As[0][0] + tid * 8;
    bf16_t* const d_a1 = &As[128][0] + tid * 8;
    bf16_t* const d_b = (tid < 256 ? &Bg[0][0] : &Bu[0][0]) + tb * 8;

    f32x4 accG[4][2], accU[4][2];
#pragma unroll
    for (int i = 0; i < 4; ++i)
#pragma unroll
        for (int j = 0; j < 2; ++j)
#pragma unroll
            for (int c = 0; c < 4; ++c) { accG[i][j][c] = 0.f; accU[i][j][c] = 0.f; }

    for (int k0 = 0; k0 < HD; k0 += BK) {
        gl16(a0, d_a0); gl16(a1, d_a1); gl16(b0, d_b);
        a0 += BK; a1 += BK; b0 += BK;
        __syncthreads();

        bf16x8 af[4], bgf[2], buf_[2];
#pragma unroll
        for (int i = 0; i < 4; ++i)
            af[i] = *(const bf16x8*)&As[wr * 64 + i * 16 + ln15][cs];
#pragma unroll
        for (int j = 0; j < 2; ++j) {
            bgf[j]  = *(const bf16x8*)&Bg[wc * 32 + j * 16 + ln15][cs];
            buf_[j] = *(const bf16x8*)&Bu[wc * 32 + j * 16 + ln15][cs];
        }
#pragma unroll
        for (int i = 0; i < 4; ++i)
#pragma unroll
            for (int j = 0; j < 2; ++j) {
                accG[i][j] = __builtin_amdgcn_mfma_f32_16x16x32_bf16(af[i], bgf[j], accG[i][j], 0, 0, 0);
                accU[i][j] = __builtin_amdgcn_mfma_f32_16x16x32_bf16(af[i], buf_[j], accU[i][j], 0, 0, 0);
            }
        __syncthreads();
    }

    // epilogue: SwiGLU in fp32, store bf16. C/D: col=lane&15, row=q*4+reg
#pragma unroll
    for (int i = 0; i < 4; ++i) {
#pragma unroll
        for (int reg = 0; reg < 4; ++reg) {
            const int rr = wr * 64 + i * 16 + q * 4 + reg;
            if (r0 + rr < rows) {
                bf16_t* dst = hbuf + (size_t)(row_base + r0 + rr) * ID + n0 + wc * 32 + ln15;
#pragma unroll
                for (int j = 0; j < 2; ++j) {
                    const float g = accG[i][j][reg], u = accU[i][j][reg];
                    dst[j * 16] = (bf16_t)((g / (1.f + __expf(-g))) * u);
                }
            }
        }
    }
}

// --------------------------------------------------------- grouped GEMM2 ----
// EXACT r9 kernel (128x128 tile, 8 waves, wave = 32x64, swizzle, ybuf stores).
__global__ __launch_bounds__(512)
void gemm2_kernel(const bf16_t* __restrict__ hbuf, const bf16_t* __restrict__ w2b,
                  const int* __restrict__ offsets, const int* __restrict__ counts,
                  const float* __restrict__ row_w,
                  const unsigned* __restrict__ tile_map, float* __restrict__ ybuf)
{
    const unsigned tm = tile_map[blockIdx.y];
    if (tm == 0xFFFFFFFFu) return;
    const int e = (int)(tm >> 16), mt = (int)(tm & 0xFFFFu);
    const int rows = counts[e];
    const int row_base = offsets[e];
    const int r0 = mt * 128;
    const int n0 = blockIdx.x * 128;

    __shared__ alignas(16) bf16_t As[128][32];
    __shared__ alignas(16) bf16_t Bs[128][32];
    __shared__ float rww_s[128];

    const int tid = threadIdx.x;
    if (tid < 128) {
        int gr = row_base + r0 + tid; if (gr > NROWS - 1) gr = NROWS - 1;
        rww_s[tid] = row_w[gr];
    }
    const int lane = tid & 63;
    const int wv = tid >> 6;
    const int wr = wv >> 1, wc = wv & 1;     // wave: rows [wr*32,+32), cols [wc*64,+64)
    const int ln15 = lane & 15, q = lane >> 4;
    const int cs = (q ^ ((ln15 >> 1) & 3)) * 8;

    const int srow = tid >> 2;
    const int scol = ((tid & 3) ^ ((tid >> 3) & 3)) * 8;
    int gr0 = row_base + r0 + srow; if (gr0 > NROWS - 1) gr0 = NROWS - 1;
    const bf16_t* a0 = hbuf + (size_t)gr0 * ID + scol;
    const bf16_t* b0 = w2b + (size_t)e * ID * HD + (size_t)(n0 + srow) * ID + scol;
    bf16_t* const d_a = &As[0][0] + tid * 8;
    bf16_t* const d_b = &Bs[0][0] + tid * 8;

    f32x4 acc[2][4];
#pragma unroll
    for (int i = 0; i < 2; ++i)
#pragma unroll
        for (int j = 0; j < 4; ++j)
#pragma unroll
            for (int c = 0; c < 4; ++c) acc[i][j][c] = 0.f;

    for (int k0 = 0; k0 < ID; k0 += BK) {
        gl16(a0, d_a); gl16(b0, d_b);
        a0 += BK; b0 += BK;
        __syncthreads();

        bf16x8 af[2], bf_[4];
#pragma unroll
        for (int i = 0; i < 2; ++i)
            af[i] = *(const bf16x8*)&As[wr * 32 + i * 16 + ln15][cs];
#pragma unroll
        for (int j = 0; j < 4; ++j)
            bf_[j] = *(const bf16x8*)&Bs[wc * 64 + j * 16 + ln15][cs];
#pragma unroll
        for (int i = 0; i < 2; ++i)
#pragma unroll
            for (int j = 0; j < 4; ++j)
                acc[i][j] = __builtin_amdgcn_mfma_f32_16x16x32_bf16(af[i], bf_[j], acc[i][j], 0, 0, 0);
        __syncthreads();
    }

    // epilogue: weighted plain stores into dense per-row buffer
#pragma unroll
    for (int i = 0; i < 2; ++i) {
#pragma unroll
        for (int reg = 0; reg < 4; ++reg) {
            const int rr = wr * 32 + i * 16 + q * 4 + reg;
            if (r0 + rr < rows) {
                const float w = rww_s[rr];
                float* dst = ybuf + (size_t)(row_base + r0 + rr) * HD + n0 + wc * 64 + ln15;
#pragma unroll
                for (int j = 0; j < 4; ++j)
                    dst[j * 16] = acc[i][j][reg] * w;
            }
        }
    }
}

// --------------------------------------------------------------- combine ----
__global__ __launch_bounds__(256)
void combine_kernel(const float* __restrict__ ybuf, const int* __restrict__ row_pos,
                    float* __restrict__ out)
{
    const int t = blockIdx.x;
    const int p0 = row_pos[t * 2 + 0], p1 = row_pos[t * 2 + 1];
    const float4 a = ((const float4*)(ybuf + (size_t)p0 * HD))[threadIdx.x];
    const float4 b = ((const float4*)(ybuf + (size_t)p1 * HD))[threadIdx.x];
    float4 o; o.x = a.x + b.x; o.y = a.y + b.y; o.z = a.z + b.z; o.w = a.w + b.w;
    ((float4*)(out + (size_t)t * HD))[threadIdx.x] = o;
}

// ---------------------------------------------------------------- launch ----
extern "C" void kernel_launch(void* const* d_in, const int* in_sizes, int n_in,
                              void* d_out, int out_size, void* d_ws, size_t ws_size,
                              hipStream_t stream) {
    const float* x   = (const float*)d_in[0];   // (4,2048,1024)
    const float* rw  = (const float*)d_in[1];   // (8,1024)
    const float* w13 = (const float*)d_in[2];   // (8,1024,4096)
    const float* w2  = (const float*)d_in[3];   // (8,2048,1024)
    float* out = (float*)d_out;                 // (4,2048,1024) fp32

    char* ws = (char*)d_ws;
    int*      counts     = (int*)(ws + 0);
    int*      cursor     = (int*)(ws + 64);
    int*      offsets    = (int*)(ws + 128);
    int*      topk_idx   = (int*)(ws + 256);
    float*    topk_w     = (float*)(ws + 256 + 1 * 65536);
    int*      token_list = (int*)(ws + 256 + 2 * 65536);
    float*    row_w      = (float*)(ws + 256 + 3 * 65536);
    int*      row_pos    = (int*)(ws + 256 + 4 * 65536);
    unsigned* map256     = (unsigned*)(ws + 256 + 5 * 65536);
    unsigned* map128     = (unsigned*)(ws + 256 + 6 * 65536);
    const size_t MB = 1024 * 1024;
    bf16_t* xb   = (bf16_t*)(ws + 1 * MB);      // 16 MiB
    bf16_t* hbuf = (bf16_t*)(ws + 17 * MB);     // 64 MiB
    bf16_t* w13b = (bf16_t*)(ws + 81 * MB);     // 64 MiB (dead after gemm1)
    float*  ybuf = (float*)(ws + 81 * MB);      // 64 MiB fp32, ALIASES w13b
                                                // (stream-ordered: gemm1 reads,
                                                //  then gemm2 overwrites)
    bf16_t* w2b  = (bf16_t*)(ws + 145 * MB);    // 32 MiB (ends at 177 MiB)

    hipMemsetAsync(ws, 0, 256, stream);         // counts/cursor/offsets

    dim3 gp1(2 * ID / 64, HD / 64, NEXP);       // w13: K=HD, N=2*ID -> [n][k]
    precast_kernel<<<gp1, 256, 0, stream>>>(w13, w13b, HD, 2 * ID);
    dim3 gp2(HD / 64, ID / 64, NEXP);           // w2: K=ID, N=HD -> [n][k]
    precast_kernel<<<gp2, 256, 0, stream>>>(w2, w2b, ID, HD);

    router_kernel<<<NTOK, 256, 0, stream>>>(x, rw, xb, topk_idx, topk_w);
    count_kernel<<<NTOK / 256, 256, 0, stream>>>(topk_idx, counts);
    scan_kernel<<<1, 64, 0, stream>>>(counts, offsets, cursor, map256, map128);
    scatter_kernel<<<NTOK / 256, 256, 0, stream>>>(topk_idx, topk_w, cursor,
                                                   token_list, row_w, row_pos);

    dim3 g1(ID / 64, MAXT1);                    // 32 x 72 = 2304 blocks
    gemm1_kernel<<<g1, 512, 0, stream>>>(xb, w13b, offsets, counts, token_list,
                                         map256, hbuf);
    dim3 g2(HD / 128, MAXT2);                   // 8 x 136
    gemm2_kernel<<<g2, 512, 0, stream>>>(hbuf, w2b, offsets, counts, row_w,
                                         map128, ybuf);
    combine_kernel<<<NTOK, 256, 0, stream>>>(ybuf, row_pos, out);
}

// Round 11
// 580.930 us; speedup vs baseline: 1.0218x; 1.0218x over previous
//
#include <hip/hip_runtime.h>
#include <hip/hip_bf16.h>
#include <math.h>

// Problem constants (AydinConfig: H=1024, I=2048, E=8, K=2; B=4, S=2048)
#define NEXP 8
#define HD 1024
#define ID 2048
#define NTOK 8192          // B*S
#define NROWS 16384        // NTOK * top_k

typedef __bf16 bf16_t;
typedef __bf16 bf16x8 __attribute__((ext_vector_type(8)));
typedef float f32x4 __attribute__((ext_vector_type(4)));

// MEASURED LEDGER (do not regress):
//  r5 atomicAdd epi +21; r6 gemm2 BN=64 +22 -> gemm2 = BN=128 + ybuf + combine.
//  r7 launch_bounds cap < need -> SPILL. Never cap below need.
//  r8 occ 31->60% flat; r9 swizzle conflicts->0, -7us, total 591 (best);
//  r10 LDS volume 1.45x down, flat. gemm1 == 192us across occ 31-61%,
//  conflicts 0-2.6e7, LDS volume +-45% => binder is the per-K-step
//  vmcnt(0)-drain + 2-barrier skeleton (2-phase structural stall, m97-type).
//  => r11: BK 32->64. Same bytes, same reads, same MFMAs; HALF the drains
//     (gemm1 32->16 steps, gemm2 64->32). Swizzle generalized to 64-col rows:
//     phys_chunk = logical ^ (row&7), both-sides (source + read), dest linear.
#define BK 64
#define MAXT1 72           // 256-row tiles: sum ceil(c/256) <= 71
#define MAXT2 136          // 128-row tiles: sum ceil(c/128) <= 135

// async global->LDS, 16B per lane. LDS dest must be wave-uniform base + lane*16.
__device__ __forceinline__ void gl16(const void* g, void* l) {
    __builtin_amdgcn_global_load_lds(
        (const __attribute__((address_space(1))) unsigned int*)g,
        (__attribute__((address_space(3))) unsigned int*)l, 16, 0, 0);
}

// ---------------------------------------------------------------- router ----
__global__ __launch_bounds__(256)
void router_kernel(const float* __restrict__ x, const float* __restrict__ rw,
                   bf16_t* __restrict__ xb, int* __restrict__ topk_idx,
                   float* __restrict__ topk_w)
{
    const int t = blockIdx.x;
    const int tid = threadIdx.x;
    const float4 xv = ((const float4*)(x + (size_t)t * HD))[tid];
    float acc[NEXP];
#pragma unroll
    for (int e = 0; e < NEXP; ++e) {
        const float4 w4 = ((const float4*)(rw + e * HD))[tid];
        acc[e] = xv.x * w4.x + xv.y * w4.y + xv.z * w4.z + xv.w * w4.w;
    }
    bf16_t tmp[4] = {(bf16_t)xv.x, (bf16_t)xv.y, (bf16_t)xv.z, (bf16_t)xv.w};
    *(uint2*)(xb + (size_t)t * HD + tid * 4) = *(const uint2*)tmp;

    __shared__ float red[4][NEXP];
    const int lane = tid & 63, wv = tid >> 6;
#pragma unroll
    for (int e = 0; e < NEXP; ++e) {
        float v = acc[e];
#pragma unroll
        for (int off = 32; off >= 1; off >>= 1) v += __shfl_down(v, off, 64);
        if (lane == 0) red[wv][e] = v;
    }
    __syncthreads();
    if (tid == 0) {
        float lg[NEXP], mx = -1e30f;
#pragma unroll
        for (int e = 0; e < NEXP; ++e) {
            lg[e] = red[0][e] + red[1][e] + red[2][e] + red[3][e];
            mx = fmaxf(mx, lg[e]);
        }
        float p[NEXP], s = 0.f;
#pragma unroll
        for (int e = 0; e < NEXP; ++e) { p[e] = __expf(lg[e] - mx); s += p[e]; }
        const float inv = 1.f / s;
#pragma unroll
        for (int e = 0; e < NEXP; ++e) p[e] *= inv;
        int i0 = 0; float p0 = p[0];
#pragma unroll
        for (int e = 1; e < NEXP; ++e) if (p[e] > p0) { p0 = p[e]; i0 = e; }
        int i1 = -1; float p1 = -1.f;
#pragma unroll
        for (int e = 0; e < NEXP; ++e) if (e != i0 && p[e] > p1) { p1 = p[e]; i1 = e; }
        const float d = 1.f / (p0 + p1 + 1e-6f);
        topk_idx[t * 2 + 0] = i0; topk_idx[t * 2 + 1] = i1;
        topk_w[t * 2 + 0] = p0 * d; topk_w[t * 2 + 1] = p1 * d;
    }
}

// ----------------------------------------------------------------- count ----
__global__ __launch_bounds__(256)
void count_kernel(const int* __restrict__ topk_idx, int* __restrict__ counts)
{
    __shared__ int lc[NEXP];
    const int tid = threadIdx.x;
    if (tid < NEXP) lc[tid] = 0;
    __syncthreads();
    const int t = blockIdx.x * 256 + tid;
    atomicAdd(&lc[topk_idx[t * 2 + 0]], 1);
    atomicAdd(&lc[topk_idx[t * 2 + 1]], 1);
    __syncthreads();
    if (tid < NEXP) atomicAdd(&counts[tid], lc[tid]);
}

// ------------------------------------------------------------------ scan ----
__global__ void scan_kernel(const int* __restrict__ counts, int* __restrict__ offsets,
                            int* __restrict__ cursor,
                            unsigned* __restrict__ map256, unsigned* __restrict__ map128)
{
    __shared__ int tb2[NEXP + 1], tb1[NEXP + 1];
    if (threadIdx.x == 0) {
        int s = 0, t2 = 0, t1 = 0;
        for (int e = 0; e < NEXP; ++e) {
            offsets[e] = s; cursor[e] = s; s += counts[e];
            tb2[e] = t2; t2 += (counts[e] + 255) >> 8;
            tb1[e] = t1; t1 += (counts[e] + 127) >> 7;
        }
        tb2[NEXP] = t2; tb1[NEXP] = t1;
    }
    __syncthreads();
    for (int i = threadIdx.x; i < MAXT1; i += 64) {
        unsigned v = 0xFFFFFFFFu;
#pragma unroll
        for (int e = 0; e < NEXP; ++e)
            if (i >= tb2[e] && i < tb2[e + 1]) v = ((unsigned)e << 16) | (unsigned)(i - tb2[e]);
        map256[i] = v;
    }
    for (int i = threadIdx.x; i < MAXT2; i += 64) {
        unsigned v = 0xFFFFFFFFu;
#pragma unroll
        for (int e = 0; e < NEXP; ++e)
            if (i >= tb1[e] && i < tb1[e + 1]) v = ((unsigned)e << 16) | (unsigned)(i - tb1[e]);
        map128[i] = v;
    }
}

// --------------------------------------------------------------- scatter ----
__global__ __launch_bounds__(256)
void scatter_kernel(const int* __restrict__ topk_idx, const float* __restrict__ topk_w,
                    int* __restrict__ cursor, int* __restrict__ token_list,
                    float* __restrict__ row_w, int* __restrict__ row_pos)
{
    __shared__ int lc[NEXP], gbase[NEXP];
    const int tid = threadIdx.x;
    if (tid < NEXP) lc[tid] = 0;
    __syncthreads();
    const int t = blockIdx.x * 256 + tid;
    const int e0 = topk_idx[t * 2 + 0], e1 = topk_idx[t * 2 + 1];
    const int lp0 = atomicAdd(&lc[e0], 1);
    const int lp1 = atomicAdd(&lc[e1], 1);
    __syncthreads();
    if (tid < NEXP) gbase[tid] = atomicAdd(&cursor[tid], lc[tid]);
    __syncthreads();
    const int p0 = gbase[e0] + lp0, p1 = gbase[e1] + lp1;
    token_list[p0] = t; row_w[p0] = topk_w[t * 2 + 0]; row_pos[t * 2 + 0] = p0;
    token_list[p1] = t; row_w[p1] = topk_w[t * 2 + 1]; row_pos[t * 2 + 1] = p1;
}

// -------------------------------------------------------- precast weights ----
__global__ __launch_bounds__(256)
void precast_kernel(const float* __restrict__ src, bf16_t* __restrict__ dst,
                    int K, int N)
{
    const int e = blockIdx.z;
    src += (size_t)e * K * N;
    dst += (size_t)e * K * N;
    const int n0 = blockIdx.x * 64, k0 = blockIdx.y * 64;
    __shared__ float tile[64][65];
    const int tid = threadIdx.x;
    const int tx = (tid & 15) * 4, ty = tid >> 4;
#pragma unroll
    for (int p = 0; p < 4; ++p) {
        const float4 v = *(const float4*)(src + (size_t)(k0 + ty + p * 16) * N + n0 + tx);
        tile[ty + p * 16][tx + 0] = v.x;
        tile[ty + p * 16][tx + 1] = v.y;
        tile[ty + p * 16][tx + 2] = v.z;
        tile[ty + p * 16][tx + 3] = v.w;
    }
    __syncthreads();
    const int n = tid >> 2, kc = (tid & 3) * 16;
    bf16_t outv[16];
#pragma unroll
    for (int j = 0; j < 16; ++j) outv[j] = (bf16_t)tile[kc + j][n];
    bf16_t* d = dst + (size_t)(n0 + n) * K + k0 + kc;
    *(uint4*)d = *(uint4*)outv;
    *(uint4*)(d + 8) = *((uint4*)outv + 1);
}

// ------------------------------------------------- grouped GEMM1 + SwiGLU ----
// 256-row x 64-swiglu-col tile, 512 thr / 8 waves, wave = 64 rows x (32g+32u).
// BK=64: 16 K-steps (half the barrier-drains). 64-col LDS rows, swizzle:
// phys_chunk = logical ^ (row&7) on gl16 SOURCE + read addr; dest linear.
__global__ __launch_bounds__(512)
void gemm1_kernel(const bf16_t* __restrict__ xb, const bf16_t* __restrict__ w13b,
                  const int* __restrict__ offsets, const int* __restrict__ counts,
                  const int* __restrict__ token_list,
                  const unsigned* __restrict__ tile_map, bf16_t* __restrict__ hbuf)
{
    const unsigned tm = tile_map[blockIdx.y];
    if (tm == 0xFFFFFFFFu) return;
    const int e = (int)(tm >> 16), mt = (int)(tm & 0xFFFFu);
    const int rows = counts[e];
    const int row_base = offsets[e];
    const int r0 = mt * 256;
    const int n0 = blockIdx.x * 64;          // swiglu-col tile (64 gate + 64 up)

    __shared__ alignas(16) bf16_t As[256][64];   // 32 KiB
    __shared__ alignas(16) bf16_t Bg[64][64];    // 8 KiB
    __shared__ alignas(16) bf16_t Bu[64][64];    // 8 KiB

    const int tid = threadIdx.x;
    const int lane = tid & 63;
    const int wv = tid >> 6;                 // 0..7
    const int wr = wv >> 1, wc = wv & 1;     // wave: rows [wr*64,+64), cols [wc*32,+32)
    const int ln15 = lane & 15, q = lane >> 4;
    const int x7 = ln15 & 7;                 // row&7 for every fragment-read row
    const int c0 = ((q ^ x7)) * 8;           // kk=0 chunk byte-elems
    const int c1 = c0 ^ 32;                  // kk=1: (q|4)^x7 = (q^x7)^4 -> +-32 elems

    // staging: slot s in [0,2048) for A (256 rows x 8 chunks), [0,512) for B each.
    // row = s>>3, phys chunk = s&7, logical chunk = (s&7) ^ ((s>>3)&7).
    const int srow = tid >> 3;               // 0..63
    const int scol = ((tid & 7) ^ ((tid >> 3) & 7)) * 8;   // p*64 doesn't affect &7
    const bf16_t* ap[4];
#pragma unroll
    for (int p = 0; p < 4; ++p) {
        int gr = row_base + r0 + p * 64 + srow;
        if (gr > NROWS - 1) gr = NROWS - 1;
        ap[p] = xb + (size_t)token_list[gr] * HD + scol;
    }
    const bf16_t* wb = w13b + (size_t)e * HD * (2 * ID);
    const bf16_t* bgp = wb + (size_t)(n0 + srow) * HD + scol;
    const bf16_t* bup = wb + (size_t)(ID + n0 + srow) * HD + scol;
    bf16_t* const d_bg = &Bg[0][0] + tid * 8;
    bf16_t* const d_bu = &Bu[0][0] + tid * 8;

    f32x4 accG[4][2], accU[4][2];
#pragma unroll
    for (int i = 0; i < 4; ++i)
#pragma unroll
        for (int j = 0; j < 2; ++j)
#pragma unroll
            for (int c = 0; c < 4; ++c) { accG[i][j][c] = 0.f; accU[i][j][c] = 0.f; }

    for (int k0 = 0; k0 < HD; k0 += BK) {
#pragma unroll
        for (int p = 0; p < 4; ++p) {
            gl16(ap[p], &As[0][0] + (p * 512 + tid) * 8);
            ap[p] += BK;
        }
        gl16(bgp, d_bg); gl16(bup, d_bu);
        bgp += BK; bup += BK;
        __syncthreads();

#pragma unroll
        for (int kk = 0; kk < 2; ++kk) {
            const int cc = kk ? c1 : c0;
            bf16x8 af[4], bgf[2], buf_[2];
#pragma unroll
            for (int i = 0; i < 4; ++i)
                af[i] = *(const bf16x8*)&As[wr * 64 + i * 16 + ln15][cc];
#pragma unroll
            for (int j = 0; j < 2; ++j) {
                bgf[j]  = *(const bf16x8*)&Bg[wc * 32 + j * 16 + ln15][cc];
                buf_[j] = *(const bf16x8*)&Bu[wc * 32 + j * 16 + ln15][cc];
            }
#pragma unroll
            for (int i = 0; i < 4; ++i)
#pragma unroll
                for (int j = 0; j < 2; ++j) {
                    accG[i][j] = __builtin_amdgcn_mfma_f32_16x16x32_bf16(af[i], bgf[j], accG[i][j], 0, 0, 0);
                    accU[i][j] = __builtin_amdgcn_mfma_f32_16x16x32_bf16(af[i], buf_[j], accU[i][j], 0, 0, 0);
                }
        }
        __syncthreads();
    }

    // epilogue: SwiGLU in fp32, store bf16. C/D: col=lane&15, row=q*4+reg
#pragma unroll
    for (int i = 0; i < 4; ++i) {
#pragma unroll
        for (int reg = 0; reg < 4; ++reg) {
            const int rr = wr * 64 + i * 16 + q * 4 + reg;
            if (r0 + rr < rows) {
                bf16_t* dst = hbuf + (size_t)(row_base + r0 + rr) * ID + n0 + wc * 32 + ln15;
#pragma unroll
                for (int j = 0; j < 2; ++j) {
                    const float g = accG[i][j][reg], u = accU[i][j][reg];
                    dst[j * 16] = (bf16_t)((g / (1.f + __expf(-g))) * u);
                }
            }
        }
    }
}

// --------------------------------------------------------- grouped GEMM2 ----
// 128x128 tile, 8 waves, wave = 32 rows x 64 cols. BK=64: 32 K-steps.
// Same 64-col swizzle. ybuf plain stores + combine (measured-best epilogue).
__global__ __launch_bounds__(512)
void gemm2_kernel(const bf16_t* __restrict__ hbuf, const bf16_t* __restrict__ w2b,
                  const int* __restrict__ offsets, const int* __restrict__ counts,
                  const float* __restrict__ row_w,
                  const unsigned* __restrict__ tile_map, float* __restrict__ ybuf)
{
    const unsigned tm = tile_map[blockIdx.y];
    if (tm == 0xFFFFFFFFu) return;
    const int e = (int)(tm >> 16), mt = (int)(tm & 0xFFFFu);
    const int rows = counts[e];
    const int row_base = offsets[e];
    const int r0 = mt * 128;
    const int n0 = blockIdx.x * 128;

    __shared__ alignas(16) bf16_t As[128][64];   // 16 KiB
    __shared__ alignas(16) bf16_t Bs[128][64];   // 16 KiB
    __shared__ float rww_s[128];

    const int tid = threadIdx.x;
    if (tid < 128) {
        int gr = row_base + r0 + tid; if (gr > NROWS - 1) gr = NROWS - 1;
        rww_s[tid] = row_w[gr];
    }
    const int lane = tid & 63;
    const int wv = tid >> 6;
    const int wr = wv >> 1, wc = wv & 1;     // wave: rows [wr*32,+32), cols [wc*64,+64)
    const int ln15 = lane & 15, q = lane >> 4;
    const int x7 = ln15 & 7;
    const int c0 = ((q ^ x7)) * 8;
    const int c1 = c0 ^ 32;

    const int srow = tid >> 3;               // 0..63
    const int scol = ((tid & 7) ^ ((tid >> 3) & 7)) * 8;
    const bf16_t* ap[2];
#pragma unroll
    for (int p = 0; p < 2; ++p) {
        int gr = row_base + r0 + p * 64 + srow;
        if (gr > NROWS - 1) gr = NROWS - 1;
        ap[p] = hbuf + (size_t)gr * ID + scol;
    }
    const bf16_t* w2e = w2b + (size_t)e * ID * HD;
    const bf16_t* bp0 = w2e + (size_t)(n0 + srow) * ID + scol;
    const bf16_t* bp1 = w2e + (size_t)(n0 + 64 + srow) * ID + scol;

    f32x4 acc[2][4];
#pragma unroll
    for (int i = 0; i < 2; ++i)
#pragma unroll
        for (int j = 0; j < 4; ++j)
#pragma unroll
            for (int c = 0; c < 4; ++c) acc[i][j][c] = 0.f;

    for (int k0 = 0; k0 < ID; k0 += BK) {
        gl16(ap[0], &As[0][0] + tid * 8);
        gl16(ap[1], &As[64][0] + tid * 8);
        gl16(bp0, &Bs[0][0] + tid * 8);
        gl16(bp1, &Bs[64][0] + tid * 8);
        ap[0] += BK; ap[1] += BK; bp0 += BK; bp1 += BK;
        __syncthreads();

#pragma unroll
        for (int kk = 0; kk < 2; ++kk) {
            const int cc = kk ? c1 : c0;
            bf16x8 af[2], bf_[4];
#pragma unroll
            for (int i = 0; i < 2; ++i)
                af[i] = *(const bf16x8*)&As[wr * 32 + i * 16 + ln15][cc];
#pragma unroll
            for (int j = 0; j < 4; ++j)
                bf_[j] = *(const bf16x8*)&Bs[wc * 64 + j * 16 + ln15][cc];
#pragma unroll
            for (int i = 0; i < 2; ++i)
#pragma unroll
                for (int j = 0; j < 4; ++j)
                    acc[i][j] = __builtin_amdgcn_mfma_f32_16x16x32_bf16(af[i], bf_[j], acc[i][j], 0, 0, 0);
        }
        __syncthreads();
    }

    // epilogue: weighted plain stores into dense per-row buffer
#pragma unroll
    for (int i = 0; i < 2; ++i) {
#pragma unroll
        for (int reg = 0; reg < 4; ++reg) {
            const int rr = wr * 32 + i * 16 + q * 4 + reg;
            if (r0 + rr < rows) {
                const float w = rww_s[rr];
                float* dst = ybuf + (size_t)(row_base + r0 + rr) * HD + n0 + wc * 64 + ln15;
#pragma unroll
                for (int j = 0; j < 4; ++j)
                    dst[j * 16] = acc[i][j][reg] * w;
            }
        }
    }
}

// --------------------------------------------------------------- combine ----
__global__ __launch_bounds__(256)
void combine_kernel(const float* __restrict__ ybuf, const int* __restrict__ row_pos,
                    float* __restrict__ out)
{
    const int t = blockIdx.x;
    const int p0 = row_pos[t * 2 + 0], p1 = row_pos[t * 2 + 1];
    const float4 a = ((const float4*)(ybuf + (size_t)p0 * HD))[threadIdx.x];
    const float4 b = ((const float4*)(ybuf + (size_t)p1 * HD))[threadIdx.x];
    float4 o; o.x = a.x + b.x; o.y = a.y + b.y; o.z = a.z + b.z; o.w = a.w + b.w;
    ((float4*)(out + (size_t)t * HD))[threadIdx.x] = o;
}

// ---------------------------------------------------------------- launch ----
extern "C" void kernel_launch(void* const* d_in, const int* in_sizes, int n_in,
                              void* d_out, int out_size, void* d_ws, size_t ws_size,
                              hipStream_t stream) {
    const float* x   = (const float*)d_in[0];   // (4,2048,1024)
    const float* rw  = (const float*)d_in[1];   // (8,1024)
    const float* w13 = (const float*)d_in[2];   // (8,1024,4096)
    const float* w2  = (const float*)d_in[3];   // (8,2048,1024)
    float* out = (float*)d_out;                 // (4,2048,1024) fp32

    char* ws = (char*)d_ws;
    int*      counts     = (int*)(ws + 0);
    int*      cursor     = (int*)(ws + 64);
    int*      offsets    = (int*)(ws + 128);
    int*      topk_idx   = (int*)(ws + 256);
    float*    topk_w     = (float*)(ws + 256 + 1 * 65536);
    int*      token_list = (int*)(ws + 256 + 2 * 65536);
    float*    row_w      = (float*)(ws + 256 + 3 * 65536);
    int*      row_pos    = (int*)(ws + 256 + 4 * 65536);
    unsigned* map256     = (unsigned*)(ws + 256 + 5 * 65536);
    unsigned* map128     = (unsigned*)(ws + 256 + 6 * 65536);
    const size_t MB = 1024 * 1024;
    bf16_t* xb   = (bf16_t*)(ws + 1 * MB);      // 16 MiB
    bf16_t* hbuf = (bf16_t*)(ws + 17 * MB);     // 64 MiB
    bf16_t* w13b = (bf16_t*)(ws + 81 * MB);     // 64 MiB (dead after gemm1)
    float*  ybuf = (float*)(ws + 81 * MB);      // 64 MiB fp32, ALIASES w13b
                                                // (stream-ordered: gemm1 reads,
                                                //  then gemm2 overwrites)
    bf16_t* w2b  = (bf16_t*)(ws + 145 * MB);    // 32 MiB (ends at 177 MiB)

    hipMemsetAsync(ws, 0, 256, stream);         // counts/cursor/offsets

    dim3 gp1(2 * ID / 64, HD / 64, NEXP);       // w13: K=HD, N=2*ID -> [n][k]
    precast_kernel<<<gp1, 256, 0, stream>>>(w13, w13b, HD, 2 * ID);
    dim3 gp2(HD / 64, ID / 64, NEXP);           // w2: K=ID, N=HD -> [n][k]
    precast_kernel<<<gp2, 256, 0, stream>>>(w2, w2b, ID, HD);

    router_kernel<<<NTOK, 256, 0, stream>>>(x, rw, xb, topk_idx, topk_w);
    count_kernel<<<NTOK / 256, 256, 0, stream>>>(topk_idx, counts);
    scan_kernel<<<1, 64, 0, stream>>>(counts, offsets, cursor, map256, map128);
    scatter_kernel<<<NTOK / 256, 256, 0, stream>>>(topk_idx, topk_w, cursor,
                                                   token_list, row_w, row_pos);

    dim3 g1(ID / 64, MAXT1);                    // 32 x 72 = 2304 blocks
    gemm1_kernel<<<g1, 512, 0, stream>>>(xb, w13b, offsets, counts, token_list,
                                         map256, hbuf);
    dim3 g2(HD / 128, MAXT2);                   // 8 x 136
    gemm2_kernel<<<g2, 512, 0, stream>>>(hbuf, w2b, offsets, counts, row_w,
                                         map128, ybuf);
    combine_kernel<<<NTOK, 256, 0, stream>>>(ybuf, row_pos, out);
}

// Round 12
// 566.581 us; speedup vs baseline: 1.0476x; 1.0253x over previous
//
#include <hip/hip_runtime.h>
#include <hip/hip_bf16.h>
#include <math.h>

// Problem constants (AydinConfig: H=1024, I=2048, E=8, K=2; B=4, S=2048)
#define NEXP 8
#define HD 1024
#define ID 2048
#define NTOK 8192          // B*S
#define NROWS 16384        // NTOK * top_k

typedef __bf16 bf16_t;
typedef __bf16 bf16x8 __attribute__((ext_vector_type(8)));
typedef float f32x4 __attribute__((ext_vector_type(4)));

// MEASURED LEDGER (do not regress):
//  r5 atomicAdd epi +21; r6 gemm2 BN=64 +22 -> gemm2 = BN=128 + ybuf + combine.
//  r7 launch_bounds cap < need -> SPILL. Never cap below need.
//  r8 occ 31->60% flat (occ not binding); r9 swizzle conflicts->0 (-7us);
//  r10 LDS volume 1.45x down flat; r11 BK 32->64: gemm1 192->168us (-12.5%),
//    MfmaUtil 38 -> DRAIN-COUNT (vmcnt(0)+barriers per K-step) is the binder,
//    roughly linear in step count.
//  => r12: (a) gemm2 BK=128 (steps 32->16; LDS 64KB but gemm2 already
//     2 blocks/CU by VGPR, so no occ loss - m132's failure mode absent);
//     (b) gemm1 XCD-chunk id swizzle (2304%8==0, bijective) so drain loads
//     hit XCD-local L2 (~200cyc) instead of HBM (~900cyc).
#define BK1 64             // gemm1 K-step
#define BK2 128            // gemm2 K-step
#define MAXT1 72           // 256-row tiles: sum ceil(c/256) <= 71
#define MAXT2 136          // 128-row tiles: sum ceil(c/128) <= 135

// async global->LDS, 16B per lane. LDS dest must be wave-uniform base + lane*16.
__device__ __forceinline__ void gl16(const void* g, void* l) {
    __builtin_amdgcn_global_load_lds(
        (const __attribute__((address_space(1))) unsigned int*)g,
        (__attribute__((address_space(3))) unsigned int*)l, 16, 0, 0);
}

// ---------------------------------------------------------------- router ----
__global__ __launch_bounds__(256)
void router_kernel(const float* __restrict__ x, const float* __restrict__ rw,
                   bf16_t* __restrict__ xb, int* __restrict__ topk_idx,
                   float* __restrict__ topk_w)
{
    const int t = blockIdx.x;
    const int tid = threadIdx.x;
    const float4 xv = ((const float4*)(x + (size_t)t * HD))[tid];
    float acc[NEXP];
#pragma unroll
    for (int e = 0; e < NEXP; ++e) {
        const float4 w4 = ((const float4*)(rw + e * HD))[tid];
        acc[e] = xv.x * w4.x + xv.y * w4.y + xv.z * w4.z + xv.w * w4.w;
    }
    bf16_t tmp[4] = {(bf16_t)xv.x, (bf16_t)xv.y, (bf16_t)xv.z, (bf16_t)xv.w};
    *(uint2*)(xb + (size_t)t * HD + tid * 4) = *(const uint2*)tmp;

    __shared__ float red[4][NEXP];
    const int lane = tid & 63, wv = tid >> 6;
#pragma unroll
    for (int e = 0; e < NEXP; ++e) {
        float v = acc[e];
#pragma unroll
        for (int off = 32; off >= 1; off >>= 1) v += __shfl_down(v, off, 64);
        if (lane == 0) red[wv][e] = v;
    }
    __syncthreads();
    if (tid == 0) {
        float lg[NEXP], mx = -1e30f;
#pragma unroll
        for (int e = 0; e < NEXP; ++e) {
            lg[e] = red[0][e] + red[1][e] + red[2][e] + red[3][e];
            mx = fmaxf(mx, lg[e]);
        }
        float p[NEXP], s = 0.f;
#pragma unroll
        for (int e = 0; e < NEXP; ++e) { p[e] = __expf(lg[e] - mx); s += p[e]; }
        const float inv = 1.f / s;
#pragma unroll
        for (int e = 0; e < NEXP; ++e) p[e] *= inv;
        int i0 = 0; float p0 = p[0];
#pragma unroll
        for (int e = 1; e < NEXP; ++e) if (p[e] > p0) { p0 = p[e]; i0 = e; }
        int i1 = -1; float p1 = -1.f;
#pragma unroll
        for (int e = 0; e < NEXP; ++e) if (e != i0 && p[e] > p1) { p1 = p[e]; i1 = e; }
        const float d = 1.f / (p0 + p1 + 1e-6f);
        topk_idx[t * 2 + 0] = i0; topk_idx[t * 2 + 1] = i1;
        topk_w[t * 2 + 0] = p0 * d; topk_w[t * 2 + 1] = p1 * d;
    }
}

// ----------------------------------------------------------------- count ----
__global__ __launch_bounds__(256)
void count_kernel(const int* __restrict__ topk_idx, int* __restrict__ counts)
{
    __shared__ int lc[NEXP];
    const int tid = threadIdx.x;
    if (tid < NEXP) lc[tid] = 0;
    __syncthreads();
    const int t = blockIdx.x * 256 + tid;
    atomicAdd(&lc[topk_idx[t * 2 + 0]], 1);
    atomicAdd(&lc[topk_idx[t * 2 + 1]], 1);
    __syncthreads();
    if (tid < NEXP) atomicAdd(&counts[tid], lc[tid]);
}

// ------------------------------------------------------------------ scan ----
__global__ void scan_kernel(const int* __restrict__ counts, int* __restrict__ offsets,
                            int* __restrict__ cursor,
                            unsigned* __restrict__ map256, unsigned* __restrict__ map128)
{
    __shared__ int tb2[NEXP + 1], tb1[NEXP + 1];
    if (threadIdx.x == 0) {
        int s = 0, t2 = 0, t1 = 0;
        for (int e = 0; e < NEXP; ++e) {
            offsets[e] = s; cursor[e] = s; s += counts[e];
            tb2[e] = t2; t2 += (counts[e] + 255) >> 8;
            tb1[e] = t1; t1 += (counts[e] + 127) >> 7;
        }
        tb2[NEXP] = t2; tb1[NEXP] = t1;
    }
    __syncthreads();
    for (int i = threadIdx.x; i < MAXT1; i += 64) {
        unsigned v = 0xFFFFFFFFu;
#pragma unroll
        for (int e = 0; e < NEXP; ++e)
            if (i >= tb2[e] && i < tb2[e + 1]) v = ((unsigned)e << 16) | (unsigned)(i - tb2[e]);
        map256[i] = v;
    }
    for (int i = threadIdx.x; i < MAXT2; i += 64) {
        unsigned v = 0xFFFFFFFFu;
#pragma unroll
        for (int e = 0; e < NEXP; ++e)
            if (i >= tb1[e] && i < tb1[e + 1]) v = ((unsigned)e << 16) | (unsigned)(i - tb1[e]);
        map128[i] = v;
    }
}

// --------------------------------------------------------------- scatter ----
__global__ __launch_bounds__(256)
void scatter_kernel(const int* __restrict__ topk_idx, const float* __restrict__ topk_w,
                    int* __restrict__ cursor, int* __restrict__ token_list,
                    float* __restrict__ row_w, int* __restrict__ row_pos)
{
    __shared__ int lc[NEXP], gbase[NEXP];
    const int tid = threadIdx.x;
    if (tid < NEXP) lc[tid] = 0;
    __syncthreads();
    const int t = blockIdx.x * 256 + tid;
    const int e0 = topk_idx[t * 2 + 0], e1 = topk_idx[t * 2 + 1];
    const int lp0 = atomicAdd(&lc[e0], 1);
    const int lp1 = atomicAdd(&lc[e1], 1);
    __syncthreads();
    if (tid < NEXP) gbase[tid] = atomicAdd(&cursor[tid], lc[tid]);
    __syncthreads();
    const int p0 = gbase[e0] + lp0, p1 = gbase[e1] + lp1;
    token_list[p0] = t; row_w[p0] = topk_w[t * 2 + 0]; row_pos[t * 2 + 0] = p0;
    token_list[p1] = t; row_w[p1] = topk_w[t * 2 + 1]; row_pos[t * 2 + 1] = p1;
}

// -------------------------------------------------------- precast weights ----
__global__ __launch_bounds__(256)
void precast_kernel(const float* __restrict__ src, bf16_t* __restrict__ dst,
                    int K, int N)
{
    const int e = blockIdx.z;
    src += (size_t)e * K * N;
    dst += (size_t)e * K * N;
    const int n0 = blockIdx.x * 64, k0 = blockIdx.y * 64;
    __shared__ float tile[64][65];
    const int tid = threadIdx.x;
    const int tx = (tid & 15) * 4, ty = tid >> 4;
#pragma unroll
    for (int p = 0; p < 4; ++p) {
        const float4 v = *(const float4*)(src + (size_t)(k0 + ty + p * 16) * N + n0 + tx);
        tile[ty + p * 16][tx + 0] = v.x;
        tile[ty + p * 16][tx + 1] = v.y;
        tile[ty + p * 16][tx + 2] = v.z;
        tile[ty + p * 16][tx + 3] = v.w;
    }
    __syncthreads();
    const int n = tid >> 2, kc = (tid & 3) * 16;
    bf16_t outv[16];
#pragma unroll
    for (int j = 0; j < 16; ++j) outv[j] = (bf16_t)tile[kc + j][n];
    bf16_t* d = dst + (size_t)(n0 + n) * K + k0 + kc;
    *(uint4*)d = *(uint4*)outv;
    *(uint4*)(d + 8) = *((uint4*)outv + 1);
}

// ------------------------------------------------- grouped GEMM1 + SwiGLU ----
// r11 kernel (256x64 tile, 512 thr, BK=64, 64-col swizzle) + XCD id swizzle:
// 2304 blocks % 8 == 0 -> bijective chunk remap; each XCD owns 288 consecutive
// ids (~9 row-tiles x 32 n-tiles) so A-row reuse is XCD-L2-local.
__global__ __launch_bounds__(512)
void gemm1_kernel(const bf16_t* __restrict__ xb, const bf16_t* __restrict__ w13b,
                  const int* __restrict__ offsets, const int* __restrict__ counts,
                  const int* __restrict__ token_list,
                  const unsigned* __restrict__ tile_map, bf16_t* __restrict__ hbuf)
{
    unsigned id = blockIdx.y * 32u + blockIdx.x;
    id = (id & 7u) * 288u + (id >> 3);       // bijective: 2304 = 8 * 288
    const unsigned tm = tile_map[id >> 5];
    if (tm == 0xFFFFFFFFu) return;
    const int e = (int)(tm >> 16), mt = (int)(tm & 0xFFFFu);
    const int rows = counts[e];
    const int row_base = offsets[e];
    const int r0 = mt * 256;
    const int n0 = (int)(id & 31u) * 64;     // swiglu-col tile (64 gate + 64 up)

    __shared__ alignas(16) bf16_t As[256][64];   // 32 KiB
    __shared__ alignas(16) bf16_t Bg[64][64];    // 8 KiB
    __shared__ alignas(16) bf16_t Bu[64][64];    // 8 KiB

    const int tid = threadIdx.x;
    const int lane = tid & 63;
    const int wv = tid >> 6;                 // 0..7
    const int wr = wv >> 1, wc = wv & 1;     // wave: rows [wr*64,+64), cols [wc*32,+32)
    const int ln15 = lane & 15, q = lane >> 4;
    const int x7 = ln15 & 7;                 // row&7 for every fragment-read row
    const int c0 = ((q ^ x7)) * 8;           // kk=0 chunk byte-elems
    const int c1 = c0 ^ 32;                  // kk=1: (q|4)^x7 = (q^x7)^4 -> +-32 elems

    const int srow = tid >> 3;               // 0..63
    const int scol = ((tid & 7) ^ ((tid >> 3) & 7)) * 8;   // p*64 doesn't affect &7
    const bf16_t* ap[4];
#pragma unroll
    for (int p = 0; p < 4; ++p) {
        int gr = row_base + r0 + p * 64 + srow;
        if (gr > NROWS - 1) gr = NROWS - 1;
        ap[p] = xb + (size_t)token_list[gr] * HD + scol;
    }
    const bf16_t* wb = w13b + (size_t)e * HD * (2 * ID);
    const bf16_t* bgp = wb + (size_t)(n0 + srow) * HD + scol;
    const bf16_t* bup = wb + (size_t)(ID + n0 + srow) * HD + scol;
    bf16_t* const d_bg = &Bg[0][0] + tid * 8;
    bf16_t* const d_bu = &Bu[0][0] + tid * 8;

    f32x4 accG[4][2], accU[4][2];
#pragma unroll
    for (int i = 0; i < 4; ++i)
#pragma unroll
        for (int j = 0; j < 2; ++j)
#pragma unroll
            for (int c = 0; c < 4; ++c) { accG[i][j][c] = 0.f; accU[i][j][c] = 0.f; }

    for (int k0 = 0; k0 < HD; k0 += BK1) {
#pragma unroll
        for (int p = 0; p < 4; ++p) {
            gl16(ap[p], &As[0][0] + (p * 512 + tid) * 8);
            ap[p] += BK1;
        }
        gl16(bgp, d_bg); gl16(bup, d_bu);
        bgp += BK1; bup += BK1;
        __syncthreads();

#pragma unroll
        for (int kk = 0; kk < 2; ++kk) {
            const int cc = kk ? c1 : c0;
            bf16x8 af[4], bgf[2], buf_[2];
#pragma unroll
            for (int i = 0; i < 4; ++i)
                af[i] = *(const bf16x8*)&As[wr * 64 + i * 16 + ln15][cc];
#pragma unroll
            for (int j = 0; j < 2; ++j) {
                bgf[j]  = *(const bf16x8*)&Bg[wc * 32 + j * 16 + ln15][cc];
                buf_[j] = *(const bf16x8*)&Bu[wc * 32 + j * 16 + ln15][cc];
            }
#pragma unroll
            for (int i = 0; i < 4; ++i)
#pragma unroll
                for (int j = 0; j < 2; ++j) {
                    accG[i][j] = __builtin_amdgcn_mfma_f32_16x16x32_bf16(af[i], bgf[j], accG[i][j], 0, 0, 0);
                    accU[i][j] = __builtin_amdgcn_mfma_f32_16x16x32_bf16(af[i], buf_[j], accU[i][j], 0, 0, 0);
                }
        }
        __syncthreads();
    }

    // epilogue: SwiGLU in fp32, store bf16. C/D: col=lane&15, row=q*4+reg
#pragma unroll
    for (int i = 0; i < 4; ++i) {
#pragma unroll
        for (int reg = 0; reg < 4; ++reg) {
            const int rr = wr * 64 + i * 16 + q * 4 + reg;
            if (r0 + rr < rows) {
                bf16_t* dst = hbuf + (size_t)(row_base + r0 + rr) * ID + n0 + wc * 32 + ln15;
#pragma unroll
                for (int j = 0; j < 2; ++j) {
                    const float g = accG[i][j][reg], u = accU[i][j][reg];
                    dst[j * 16] = (bf16_t)((g / (1.f + __expf(-g))) * u);
                }
            }
        }
    }
}

// --------------------------------------------------------- grouped GEMM2 ----
// 128x128 tile, 8 waves, wave = 32 rows x 64 cols. BK=128: 16 K-steps (half
// of r11's 32 -> half the vmcnt(0)-drains). LDS 64KB (still 2 blocks/CU: VGPR
// already caps there). 128-col swizzle: phys chunk = logical ^ (row&15);
// row&15 == ln15 in every fragment read, == (tid>>4)&15 in staging (32p%16=0).
__global__ __launch_bounds__(512)
void gemm2_kernel(const bf16_t* __restrict__ hbuf, const bf16_t* __restrict__ w2b,
                  const int* __restrict__ offsets, const int* __restrict__ counts,
                  const float* __restrict__ row_w,
                  const unsigned* __restrict__ tile_map, float* __restrict__ ybuf)
{
    const unsigned tm = tile_map[blockIdx.y];
    if (tm == 0xFFFFFFFFu) return;
    const int e = (int)(tm >> 16), mt = (int)(tm & 0xFFFFu);
    const int rows = counts[e];
    const int row_base = offsets[e];
    const int r0 = mt * 128;
    const int n0 = blockIdx.x * 128;

    __shared__ alignas(16) bf16_t As[128][128];  // 32 KiB
    __shared__ alignas(16) bf16_t Bs[128][128];  // 32 KiB
    __shared__ float rww_s[128];

    const int tid = threadIdx.x;
    if (tid < 128) {
        int gr = row_base + r0 + tid; if (gr > NROWS - 1) gr = NROWS - 1;
        rww_s[tid] = row_w[gr];
    }
    const int lane = tid & 63;
    const int wv = tid >> 6;
    const int wr = wv >> 1, wc = wv & 1;     // wave: rows [wr*32,+32), cols [wc*64,+64)
    const int ln15 = lane & 15, q = lane >> 4;

    // staging: slot = p*512 + tid; row = slot>>4 = p*32 + (tid>>4); chunk = tid&15
    const int srow = tid >> 4;               // 0..31 (row within 32-row stripe)
    const int scol = ((tid & 15) ^ ((tid >> 4) & 15)) * 8;
    const bf16_t* ap[4];
    const bf16_t* bp[4];
    const bf16_t* w2e = w2b + (size_t)e * ID * HD;
#pragma unroll
    for (int p = 0; p < 4; ++p) {
        int gr = row_base + r0 + p * 32 + srow;
        if (gr > NROWS - 1) gr = NROWS - 1;
        ap[p] = hbuf + (size_t)gr * ID + scol;
        bp[p] = w2e + (size_t)(n0 + p * 32 + srow) * ID + scol;
    }

    f32x4 acc[2][4];
#pragma unroll
    for (int i = 0; i < 2; ++i)
#pragma unroll
        for (int j = 0; j < 4; ++j)
#pragma unroll
            for (int c = 0; c < 4; ++c) acc[i][j][c] = 0.f;

    for (int k0 = 0; k0 < ID; k0 += BK2) {
#pragma unroll
        for (int p = 0; p < 4; ++p) {
            gl16(ap[p], &As[0][0] + (p * 512 + tid) * 8);
            gl16(bp[p], &Bs[0][0] + (p * 512 + tid) * 8);
            ap[p] += BK2; bp[p] += BK2;
        }
        __syncthreads();

#pragma unroll
        for (int kk = 0; kk < 4; ++kk) {
            const int cc = ((kk * 4 + q) ^ ln15) * 8;
            bf16x8 af[2], bf_[4];
#pragma unroll
            for (int i = 0; i < 2; ++i)
                af[i] = *(const bf16x8*)&As[wr * 32 + i * 16 + ln15][cc];
#pragma unroll
            for (int j = 0; j < 4; ++j)
                bf_[j] = *(const bf16x8*)&Bs[wc * 64 + j * 16 + ln15][cc];
#pragma unroll
            for (int i = 0; i < 2; ++i)
#pragma unroll
                for (int j = 0; j < 4; ++j)
                    acc[i][j] = __builtin_amdgcn_mfma_f32_16x16x32_bf16(af[i], bf_[j], acc[i][j], 0, 0, 0);
        }
        __syncthreads();
    }

    // epilogue: weighted plain stores into dense per-row buffer
#pragma unroll
    for (int i = 0; i < 2; ++i) {
#pragma unroll
        for (int reg = 0; reg < 4; ++reg) {
            const int rr = wr * 32 + i * 16 + q * 4 + reg;
            if (r0 + rr < rows) {
                const float w = rww_s[rr];
                float* dst = ybuf + (size_t)(row_base + r0 + rr) * HD + n0 + wc * 64 + ln15;
#pragma unroll
                for (int j = 0; j < 4; ++j)
                    dst[j * 16] = acc[i][j][reg] * w;
            }
        }
    }
}

// --------------------------------------------------------------- combine ----
__global__ __launch_bounds__(256)
void combine_kernel(const float* __restrict__ ybuf, const int* __restrict__ row_pos,
                    float* __restrict__ out)
{
    const int t = blockIdx.x;
    const int p0 = row_pos[t * 2 + 0], p1 = row_pos[t * 2 + 1];
    const float4 a = ((const float4*)(ybuf + (size_t)p0 * HD))[threadIdx.x];
    const float4 b = ((const float4*)(ybuf + (size_t)p1 * HD))[threadIdx.x];
    float4 o; o.x = a.x + b.x; o.y = a.y + b.y; o.z = a.z + b.z; o.w = a.w + b.w;
    ((float4*)(out + (size_t)t * HD))[threadIdx.x] = o;
}

// ---------------------------------------------------------------- launch ----
extern "C" void kernel_launch(void* const* d_in, const int* in_sizes, int n_in,
                              void* d_out, int out_size, void* d_ws, size_t ws_size,
                              hipStream_t stream) {
    const float* x   = (const float*)d_in[0];   // (4,2048,1024)
    const float* rw  = (const float*)d_in[1];   // (8,1024)
    const float* w13 = (const float*)d_in[2];   // (8,1024,4096)
    const float* w2  = (const float*)d_in[3];   // (8,2048,1024)
    float* out = (float*)d_out;                 // (4,2048,1024) fp32

    char* ws = (char*)d_ws;
    int*      counts     = (int*)(ws + 0);
    int*      cursor     = (int*)(ws + 64);
    int*      offsets    = (int*)(ws + 128);
    int*      topk_idx   = (int*)(ws + 256);
    float*    topk_w     = (float*)(ws + 256 + 1 * 65536);
    int*      token_list = (int*)(ws + 256 + 2 * 65536);
    float*    row_w      = (float*)(ws + 256 + 3 * 65536);
    int*      row_pos    = (int*)(ws + 256 + 4 * 65536);
    unsigned* map256     = (unsigned*)(ws + 256 + 5 * 65536);
    unsigned* map128     = (unsigned*)(ws + 256 + 6 * 65536);
    const size_t MB = 1024 * 1024;
    bf16_t* xb   = (bf16_t*)(ws + 1 * MB);      // 16 MiB
    bf16_t* hbuf = (bf16_t*)(ws + 17 * MB);     // 64 MiB
    bf16_t* w13b = (bf16_t*)(ws + 81 * MB);     // 64 MiB (dead after gemm1)
    float*  ybuf = (float*)(ws + 81 * MB);      // 64 MiB fp32, ALIASES w13b
                                                // (stream-ordered: gemm1 reads,
                                                //  then gemm2 overwrites)
    bf16_t* w2b  = (bf16_t*)(ws + 145 * MB);    // 32 MiB (ends at 177 MiB)

    hipMemsetAsync(ws, 0, 256, stream);         // counts/cursor/offsets

    dim3 gp1(2 * ID / 64, HD / 64, NEXP);       // w13: K=HD, N=2*ID -> [n][k]
    precast_kernel<<<gp1, 256, 0, stream>>>(w13, w13b, HD, 2 * ID);
    dim3 gp2(HD / 64, ID / 64, NEXP);           // w2: K=ID, N=HD -> [n][k]
    precast_kernel<<<gp2, 256, 0, stream>>>(w2, w2b, ID, HD);

    router_kernel<<<NTOK, 256, 0, stream>>>(x, rw, xb, topk_idx, topk_w);
    count_kernel<<<NTOK / 256, 256, 0, stream>>>(topk_idx, counts);
    scan_kernel<<<1, 64, 0, stream>>>(counts, offsets, cursor, map256, map128);
    scatter_kernel<<<NTOK / 256, 256, 0, stream>>>(topk_idx, topk_w, cursor,
                                                   token_list, row_w, row_pos);

    dim3 g1(ID / 64, MAXT1);                    // 32 x 72 = 2304 blocks (8 | 2304)
    gemm1_kernel<<<g1, 512, 0, stream>>>(xb, w13b, offsets, counts, token_list,
                                         map256, hbuf);
    dim3 g2(HD / 128, MAXT2);                   // 8 x 136
    gemm2_kernel<<<g2, 512, 0, stream>>>(hbuf, w2b, offsets, counts, row_w,
                                         map128, ybuf);
    combine_kernel<<<NTOK, 256, 0, stream>>>(ybuf, row_pos, out);
}

// Round 13
// 566.423 us; speedup vs baseline: 1.0479x; 1.0003x over previous
//
#include <hip/hip_runtime.h>
#include <hip/hip_bf16.h>
#include <math.h>

// Problem constants (AydinConfig: H=1024, I=2048, E=8, K=2; B=4, S=2048)
#define NEXP 8
#define HD 1024
#define ID 2048
#define NTOK 8192          // B*S
#define NROWS 16384        // NTOK * top_k

typedef __bf16 bf16_t;
typedef __bf16 bf16x8 __attribute__((ext_vector_type(8)));
typedef float f32x4 __attribute__((ext_vector_type(4)));

// MEASURED LEDGER (do not regress):
//  r5 atomicAdd epi +21; r6 gemm2 BN=64 +22 -> gemm2 = BN=128 + ybuf + combine.
//  r7 launch_bounds cap < need -> SPILL. Never cap below need.
//  r8 occ 31->60% flat (occ not binding); r9 swizzle conflicts->0 (-7us);
//  r10 LDS volume 1.45x down flat; r11 BK 32->64 gemm1 -12.5%;
//  r12 gemm1 XCD swizzle -8us + gemm2 BK=128 -> total 566. Binder = per-step
//  vmcnt(0) drains (confirmed twice, ~linear in step count).
//  => r13: gemm1 3-slot ring, prefetch dist 1, ONE raw s_barrier/step,
//     counted vmcnt(3) (m201 discipline: raw barrier + counted waits DO work
//     at HIP level; r3's null was 1-block/CU confounded). BK back to 32
//     (slot 24KB x3 = 72KB -> 2 blocks/CU). gemm2: r12 structure + XCD swizzle
//     only (isolates ring risk to gemm1).
#define BK1 32             // gemm1 K-step (ring)
#define BK2 128            // gemm2 K-step
#define MAXT1 72           // 256-row tiles: sum ceil(c/256) <= 71
#define MAXT2 136          // 128-row tiles: sum ceil(c/128) <= 135
#define SLOT1 12288        // gemm1 ring slot elems: A 8192 + Bg 2048 + Bu 2048

// async global->LDS, 16B per lane. LDS dest must be wave-uniform base + lane*16.
__device__ __forceinline__ void gl16(const void* g, void* l) {
    __builtin_amdgcn_global_load_lds(
        (const __attribute__((address_space(1))) unsigned int*)g,
        (__attribute__((address_space(3))) unsigned int*)l, 16, 0, 0);
}

// ---------------------------------------------------------------- router ----
__global__ __launch_bounds__(256)
void router_kernel(const float* __restrict__ x, const float* __restrict__ rw,
                   bf16_t* __restrict__ xb, int* __restrict__ topk_idx,
                   float* __restrict__ topk_w)
{
    const int t = blockIdx.x;
    const int tid = threadIdx.x;
    const float4 xv = ((const float4*)(x + (size_t)t * HD))[tid];
    float acc[NEXP];
#pragma unroll
    for (int e = 0; e < NEXP; ++e) {
        const float4 w4 = ((const float4*)(rw + e * HD))[tid];
        acc[e] = xv.x * w4.x + xv.y * w4.y + xv.z * w4.z + xv.w * w4.w;
    }
    bf16_t tmp[4] = {(bf16_t)xv.x, (bf16_t)xv.y, (bf16_t)xv.z, (bf16_t)xv.w};
    *(uint2*)(xb + (size_t)t * HD + tid * 4) = *(const uint2*)tmp;

    __shared__ float red[4][NEXP];
    const int lane = tid & 63, wv = tid >> 6;
#pragma unroll
    for (int e = 0; e < NEXP; ++e) {
        float v = acc[e];
#pragma unroll
        for (int off = 32; off >= 1; off >>= 1) v += __shfl_down(v, off, 64);
        if (lane == 0) red[wv][e] = v;
    }
    __syncthreads();
    if (tid == 0) {
        float lg[NEXP], mx = -1e30f;
#pragma unroll
        for (int e = 0; e < NEXP; ++e) {
            lg[e] = red[0][e] + red[1][e] + red[2][e] + red[3][e];
            mx = fmaxf(mx, lg[e]);
        }
        float p[NEXP], s = 0.f;
#pragma unroll
        for (int e = 0; e < NEXP; ++e) { p[e] = __expf(lg[e] - mx); s += p[e]; }
        const float inv = 1.f / s;
#pragma unroll
        for (int e = 0; e < NEXP; ++e) p[e] *= inv;
        int i0 = 0; float p0 = p[0];
#pragma unroll
        for (int e = 1; e < NEXP; ++e) if (p[e] > p0) { p0 = p[e]; i0 = e; }
        int i1 = -1; float p1 = -1.f;
#pragma unroll
        for (int e = 0; e < NEXP; ++e) if (e != i0 && p[e] > p1) { p1 = p[e]; i1 = e; }
        const float d = 1.f / (p0 + p1 + 1e-6f);
        topk_idx[t * 2 + 0] = i0; topk_idx[t * 2 + 1] = i1;
        topk_w[t * 2 + 0] = p0 * d; topk_w[t * 2 + 1] = p1 * d;
    }
}

// ----------------------------------------------------------------- count ----
__global__ __launch_bounds__(256)
void count_kernel(const int* __restrict__ topk_idx, int* __restrict__ counts)
{
    __shared__ int lc[NEXP];
    const int tid = threadIdx.x;
    if (tid < NEXP) lc[tid] = 0;
    __syncthreads();
    const int t = blockIdx.x * 256 + tid;
    atomicAdd(&lc[topk_idx[t * 2 + 0]], 1);
    atomicAdd(&lc[topk_idx[t * 2 + 1]], 1);
    __syncthreads();
    if (tid < NEXP) atomicAdd(&counts[tid], lc[tid]);
}

// ------------------------------------------------------------------ scan ----
__global__ void scan_kernel(const int* __restrict__ counts, int* __restrict__ offsets,
                            int* __restrict__ cursor,
                            unsigned* __restrict__ map256, unsigned* __restrict__ map128)
{
    __shared__ int tb2[NEXP + 1], tb1[NEXP + 1];
    if (threadIdx.x == 0) {
        int s = 0, t2 = 0, t1 = 0;
        for (int e = 0; e < NEXP; ++e) {
            offsets[e] = s; cursor[e] = s; s += counts[e];
            tb2[e] = t2; t2 += (counts[e] + 255) >> 8;
            tb1[e] = t1; t1 += (counts[e] + 127) >> 7;
        }
        tb2[NEXP] = t2; tb1[NEXP] = t1;
    }
    __syncthreads();
    for (int i = threadIdx.x; i < MAXT1; i += 64) {
        unsigned v = 0xFFFFFFFFu;
#pragma unroll
        for (int e = 0; e < NEXP; ++e)
            if (i >= tb2[e] && i < tb2[e + 1]) v = ((unsigned)e << 16) | (unsigned)(i - tb2[e]);
        map256[i] = v;
    }
    for (int i = threadIdx.x; i < MAXT2; i += 64) {
        unsigned v = 0xFFFFFFFFu;
#pragma unroll
        for (int e = 0; e < NEXP; ++e)
            if (i >= tb1[e] && i < tb1[e + 1]) v = ((unsigned)e << 16) | (unsigned)(i - tb1[e]);
        map128[i] = v;
    }
}

// --------------------------------------------------------------- scatter ----
__global__ __launch_bounds__(256)
void scatter_kernel(const int* __restrict__ topk_idx, const float* __restrict__ topk_w,
                    int* __restrict__ cursor, int* __restrict__ token_list,
                    float* __restrict__ row_w, int* __restrict__ row_pos)
{
    __shared__ int lc[NEXP], gbase[NEXP];
    const int tid = threadIdx.x;
    if (tid < NEXP) lc[tid] = 0;
    __syncthreads();
    const int t = blockIdx.x * 256 + tid;
    const int e0 = topk_idx[t * 2 + 0], e1 = topk_idx[t * 2 + 1];
    const int lp0 = atomicAdd(&lc[e0], 1);
    const int lp1 = atomicAdd(&lc[e1], 1);
    __syncthreads();
    if (tid < NEXP) gbase[tid] = atomicAdd(&cursor[tid], lc[tid]);
    __syncthreads();
    const int p0 = gbase[e0] + lp0, p1 = gbase[e1] + lp1;
    token_list[p0] = t; row_w[p0] = topk_w[t * 2 + 0]; row_pos[t * 2 + 0] = p0;
    token_list[p1] = t; row_w[p1] = topk_w[t * 2 + 1]; row_pos[t * 2 + 1] = p1;
}

// -------------------------------------------------------- precast weights ----
__global__ __launch_bounds__(256)
void precast_kernel(const float* __restrict__ src, bf16_t* __restrict__ dst,
                    int K, int N)
{
    const int e = blockIdx.z;
    src += (size_t)e * K * N;
    dst += (size_t)e * K * N;
    const int n0 = blockIdx.x * 64, k0 = blockIdx.y * 64;
    __shared__ float tile[64][65];
    const int tid = threadIdx.x;
    const int tx = (tid & 15) * 4, ty = tid >> 4;
#pragma unroll
    for (int p = 0; p < 4; ++p) {
        const float4 v = *(const float4*)(src + (size_t)(k0 + ty + p * 16) * N + n0 + tx);
        tile[ty + p * 16][tx + 0] = v.x;
        tile[ty + p * 16][tx + 1] = v.y;
        tile[ty + p * 16][tx + 2] = v.z;
        tile[ty + p * 16][tx + 3] = v.w;
    }
    __syncthreads();
    const int n = tid >> 2, kc = (tid & 3) * 16;
    bf16_t outv[16];
#pragma unroll
    for (int j = 0; j < 16; ++j) outv[j] = (bf16_t)tile[kc + j][n];
    bf16_t* d = dst + (size_t)(n0 + n) * K + k0 + kc;
    *(uint4*)d = *(uint4*)outv;
    *(uint4*)(d + 8) = *((uint4*)outv + 1);
}

// ------------------------------------------------- grouped GEMM1 + SwiGLU ----
// 256x64 tile, 512 thr / 8 waves, wave = 64 rows x (32g+32u). 3-slot LDS ring,
// BK=32, prefetch distance 1, ONE raw s_barrier per step, counted vmcnt(3).
// Slot layout (elems): A[256][32] @0, Bg[64][32] @8192, Bu[64][32] @10240.
// Involution swizzle (r9-verified): phys chunk = logical ^ ((row>>1)&3) on
// gl16 SOURCE + read addr; LDS dest linear. XCD id swizzle (r12-verified).
__global__ __launch_bounds__(512)
void gemm1_kernel(const bf16_t* __restrict__ xb, const bf16_t* __restrict__ w13b,
                  const int* __restrict__ offsets, const int* __restrict__ counts,
                  const int* __restrict__ token_list,
                  const unsigned* __restrict__ tile_map, bf16_t* __restrict__ hbuf)
{
    unsigned id = blockIdx.y * 32u + blockIdx.x;
    id = (id & 7u) * 288u + (id >> 3);       // bijective: 2304 = 8 * 288
    const unsigned tm = tile_map[id >> 5];
    if (tm == 0xFFFFFFFFu) return;
    const int e = (int)(tm >> 16), mt = (int)(tm & 0xFFFFu);
    const int rows = counts[e];
    const int row_base = offsets[e];
    const int r0 = mt * 256;
    const int n0 = (int)(id & 31u) * 64;     // swiglu-col tile (64 gate + 64 up)

    __shared__ alignas(16) bf16_t lds1[3 * SLOT1];   // 72 KiB

    const int tid = threadIdx.x;
    const int lane = tid & 63;
    const int wv = tid >> 6;
    const int wr = wv >> 1, wc = wv & 1;     // wave: rows [wr*64,+64), cols [wc*32,+32)
    const int ln15 = lane & 15, q = lane >> 4;
    const int cs = (q ^ ((ln15 >> 1) & 3)) * 8;   // swizzled read chunk

    // staging: A rows tid>>2 (+128 for 2nd issue); B: waves 0-3 gate, 4-7 up
    const int srowA = tid >> 2;
    const int scol = ((tid & 3) ^ ((tid >> 3) & 3)) * 8;
    const int tb = tid & 255;
    const int srowB = tb >> 2;
    const int scolB = ((tb & 3) ^ ((tb >> 3) & 3)) * 8;
    int grA0 = row_base + r0 + srowA;       if (grA0 > NROWS - 1) grA0 = NROWS - 1;
    int grA1 = row_base + r0 + 128 + srowA; if (grA1 > NROWS - 1) grA1 = NROWS - 1;
    const bf16_t* ap0 = xb + (size_t)token_list[grA0] * HD + scol;
    const bf16_t* ap1 = xb + (size_t)token_list[grA1] * HD + scol;
    const bf16_t* wb = w13b + (size_t)e * HD * (2 * ID);
    const bf16_t* bp0 = wb + (size_t)((tid < 256 ? 0 : ID) + n0 + srowB) * HD + scolB;
    const int boff = (tid < 256 ? 8192 : 10240) + tb * 8;

    f32x4 accG[4][2], accU[4][2];
#pragma unroll
    for (int i = 0; i < 4; ++i)
#pragma unroll
        for (int j = 0; j < 2; ++j)
#pragma unroll
            for (int c = 0; c < 4; ++c) { accG[i][j][c] = 0.f; accU[i][j][c] = 0.f; }

#define G1_STG(SB, KT) do { \
    const int kk_ = (KT) * BK1; \
    gl16(ap0 + kk_, lds1 + (SB) + tid * 8); \
    gl16(ap1 + kk_, lds1 + (SB) + 4096 + tid * 8); \
    gl16(bp0 + kk_, lds1 + (SB) + boff); \
} while (0)

#define G1_COMP(SB) do { \
    const bf16_t* A_  = lds1 + (SB); \
    const bf16_t* BG_ = lds1 + (SB) + 8192; \
    const bf16_t* BU_ = lds1 + (SB) + 10240; \
    bf16x8 af[4], bgf[2], buf_[2]; \
    _Pragma("unroll") \
    for (int i_ = 0; i_ < 4; ++i_) \
        af[i_] = *(const bf16x8*)&A_[(wr * 64 + i_ * 16 + ln15) * 32 + cs]; \
    _Pragma("unroll") \
    for (int j_ = 0; j_ < 2; ++j_) { \
        bgf[j_]  = *(const bf16x8*)&BG_[(wc * 32 + j_ * 16 + ln15) * 32 + cs]; \
        buf_[j_] = *(const bf16x8*)&BU_[(wc * 32 + j_ * 16 + ln15) * 32 + cs]; \
    } \
    _Pragma("unroll") \
    for (int i_ = 0; i_ < 4; ++i_) \
        _Pragma("unroll") \
        for (int j_ = 0; j_ < 2; ++j_) { \
            accG[i_][j_] = __builtin_amdgcn_mfma_f32_16x16x32_bf16(af[i_], bgf[j_], accG[i_][j_], 0, 0, 0); \
            accU[i_][j_] = __builtin_amdgcn_mfma_f32_16x16x32_bf16(af[i_], buf_[j_], accU[i_][j_], 0, 0, 0); \
        } \
} while (0)

    // Exact-count preamble: materialize all prologue loads, then drain vmcnt
    // so in-loop counts (3 loads/stage) are precise.
    asm volatile("" :: "s"(rows), "s"(row_base));
    asm volatile("" :: "v"(ap0), "v"(ap1), "v"(bp0));
    asm volatile("s_waitcnt vmcnt(0)" ::: "memory");

    G1_STG(0, 0);                            // outstanding = 3
    int sc = 0, ss = SLOT1;
    // Ring invariant at iter t: slot t%3 staged (its 3 loads are the oldest
    // outstanding), slot (t+1)%3 being staged now. vmcnt(3) completes slot t;
    // barrier publishes all waves' slot-t stores; compute reads slot t.
    // Overwrite safety: stage(t+1) targets the slot computed at t-2, and all
    // waves passed barrier(t-1) => finished compute(t-2).  [N=3 >= d+2, d=1]
    for (int t = 0; t < 31; ++t) {
        G1_STG(ss, t + 1);                   // outstanding = 6
        asm volatile("s_waitcnt vmcnt(3)" ::: "memory");
        __builtin_amdgcn_s_barrier();
        __builtin_amdgcn_sched_barrier(0);
        G1_COMP(sc);
        sc = ss; ss += SLOT1; if (ss == 3 * SLOT1) ss = 0;
    }
    asm volatile("s_waitcnt vmcnt(0)" ::: "memory");
    __builtin_amdgcn_s_barrier();
    __builtin_amdgcn_sched_barrier(0);
    G1_COMP(sc);
#undef G1_STG
#undef G1_COMP

    // epilogue: SwiGLU in fp32, store bf16. C/D: col=lane&15, row=q*4+reg
#pragma unroll
    for (int i = 0; i < 4; ++i) {
#pragma unroll
        for (int reg = 0; reg < 4; ++reg) {
            const int rr = wr * 64 + i * 16 + q * 4 + reg;
            if (r0 + rr < rows) {
                bf16_t* dst = hbuf + (size_t)(row_base + r0 + rr) * ID + n0 + wc * 32 + ln15;
#pragma unroll
                for (int j = 0; j < 2; ++j) {
                    const float g = accG[i][j][reg], u = accU[i][j][reg];
                    dst[j * 16] = (bf16_t)((g / (1.f + __expf(-g))) * u);
                }
            }
        }
    }
}

// --------------------------------------------------------- grouped GEMM2 ----
// r12 kernel (128x128 tile, BK=128, 16 steps, 128-col swizzle) + XCD swizzle
// (1088 = 8 x 136, bijective). Structure otherwise untouched.
__global__ __launch_bounds__(512)
void gemm2_kernel(const bf16_t* __restrict__ hbuf, const bf16_t* __restrict__ w2b,
                  const int* __restrict__ offsets, const int* __restrict__ counts,
                  const float* __restrict__ row_w,
                  const unsigned* __restrict__ tile_map, float* __restrict__ ybuf)
{
    unsigned id = blockIdx.y * 8u + blockIdx.x;
    id = (id & 7u) * 136u + (id >> 3);       // bijective: 1088 = 8 * 136
    const unsigned tm = tile_map[id >> 3];
    if (tm == 0xFFFFFFFFu) return;
    const int e = (int)(tm >> 16), mt = (int)(tm & 0xFFFFu);
    const int rows = counts[e];
    const int row_base = offsets[e];
    const int r0 = mt * 128;
    const int n0 = (int)(id & 7u) * 128;

    __shared__ alignas(16) bf16_t As[128][128];  // 32 KiB
    __shared__ alignas(16) bf16_t Bs[128][128];  // 32 KiB
    __shared__ float rww_s[128];

    const int tid = threadIdx.x;
    if (tid < 128) {
        int gr = row_base + r0 + tid; if (gr > NROWS - 1) gr = NROWS - 1;
        rww_s[tid] = row_w[gr];
    }
    const int lane = tid & 63;
    const int wv = tid >> 6;
    const int wr = wv >> 1, wc = wv & 1;     // wave: rows [wr*32,+32), cols [wc*64,+64)
    const int ln15 = lane & 15, q = lane >> 4;

    const int srow = tid >> 4;               // 0..31 (row within 32-row stripe)
    const int scol = ((tid & 15) ^ ((tid >> 4) & 15)) * 8;
    const bf16_t* ap[4];
    const bf16_t* bp[4];
    const bf16_t* w2e = w2b + (size_t)e * ID * HD;
#pragma unroll
    for (int p = 0; p < 4; ++p) {
        int gr = row_base + r0 + p * 32 + srow;
        if (gr > NROWS - 1) gr = NROWS - 1;
        ap[p] = hbuf + (size_t)gr * ID + scol;
        bp[p] = w2e + (size_t)(n0 + p * 32 + srow) * ID + scol;
    }

    f32x4 acc[2][4];
#pragma unroll
    for (int i = 0; i < 2; ++i)
#pragma unroll
        for (int j = 0; j < 4; ++j)
#pragma unroll
            for (int c = 0; c < 4; ++c) acc[i][j][c] = 0.f;

    for (int k0 = 0; k0 < ID; k0 += BK2) {
#pragma unroll
        for (int p = 0; p < 4; ++p) {
            gl16(ap[p], &As[0][0] + (p * 512 + tid) * 8);
            gl16(bp[p], &Bs[0][0] + (p * 512 + tid) * 8);
            ap[p] += BK2; bp[p] += BK2;
        }
        __syncthreads();

#pragma unroll
        for (int kk = 0; kk < 4; ++kk) {
            const int cc = ((kk * 4 + q) ^ ln15) * 8;
            bf16x8 af[2], bf_[4];
#pragma unroll
            for (int i = 0; i < 2; ++i)
                af[i] = *(const bf16x8*)&As[wr * 32 + i * 16 + ln15][cc];
#pragma unroll
            for (int j = 0; j < 4; ++j)
                bf_[j] = *(const bf16x8*)&Bs[wc * 64 + j * 16 + ln15][cc];
#pragma unroll
            for (int i = 0; i < 2; ++i)
#pragma unroll
                for (int j = 0; j < 4; ++j)
                    acc[i][j] = __builtin_amdgcn_mfma_f32_16x16x32_bf16(af[i], bf_[j], acc[i][j], 0, 0, 0);
        }
        __syncthreads();
    }

    // epilogue: weighted plain stores into dense per-row buffer
#pragma unroll
    for (int i = 0; i < 2; ++i) {
#pragma unroll
        for (int reg = 0; reg < 4; ++reg) {
            const int rr = wr * 32 + i * 16 + q * 4 + reg;
            if (r0 + rr < rows) {
                const float w = rww_s[rr];
                float* dst = ybuf + (size_t)(row_base + r0 + rr) * HD + n0 + wc * 64 + ln15;
#pragma unroll
                for (int j = 0; j < 4; ++j)
                    dst[j * 16] = acc[i][j][reg] * w;
            }
        }
    }
}

// --------------------------------------------------------------- combine ----
__global__ __launch_bounds__(256)
void combine_kernel(const float* __restrict__ ybuf, const int* __restrict__ row_pos,
                    float* __restrict__ out)
{
    const int t = blockIdx.x;
    const int p0 = row_pos[t * 2 + 0], p1 = row_pos[t * 2 + 1];
    const float4 a = ((const float4*)(ybuf + (size_t)p0 * HD))[threadIdx.x];
    const float4 b = ((const float4*)(ybuf + (size_t)p1 * HD))[threadIdx.x];
    float4 o; o.x = a.x + b.x; o.y = a.y + b.y; o.z = a.z + b.z; o.w = a.w + b.w;
    ((float4*)(out + (size_t)t * HD))[threadIdx.x] = o;
}

// ---------------------------------------------------------------- launch ----
extern "C" void kernel_launch(void* const* d_in, const int* in_sizes, int n_in,
                              void* d_out, int out_size, void* d_ws, size_t ws_size,
                              hipStream_t stream) {
    const float* x   = (const float*)d_in[0];   // (4,2048,1024)
    const float* rw  = (const float*)d_in[1];   // (8,1024)
    const float* w13 = (const float*)d_in[2];   // (8,1024,4096)
    const float* w2  = (const float*)d_in[3];   // (8,2048,1024)
    float* out = (float*)d_out;                 // (4,2048,1024) fp32

    char* ws = (char*)d_ws;
    int*      counts     = (int*)(ws + 0);
    int*      cursor     = (int*)(ws + 64);
    int*      offsets    = (int*)(ws + 128);
    int*      topk_idx   = (int*)(ws + 256);
    float*    topk_w     = (float*)(ws + 256 + 1 * 65536);
    int*      token_list = (int*)(ws + 256 + 2 * 65536);
    float*    row_w      = (float*)(ws + 256 + 3 * 65536);
    int*      row_pos    = (int*)(ws + 256 + 4 * 65536);
    unsigned* map256     = (unsigned*)(ws + 256 + 5 * 65536);
    unsigned* map128     = (unsigned*)(ws + 256 + 6 * 65536);
    const size_t MB = 1024 * 1024;
    bf16_t* xb   = (bf16_t*)(ws + 1 * MB);      // 16 MiB
    bf16_t* hbuf = (bf16_t*)(ws + 17 * MB);     // 64 MiB
    bf16_t* w13b = (bf16_t*)(ws + 81 * MB);     // 64 MiB (dead after gemm1)
    float*  ybuf = (float*)(ws + 81 * MB);      // 64 MiB fp32, ALIASES w13b
                                                // (stream-ordered: gemm1 reads,
                                                //  then gemm2 overwrites)
    bf16_t* w2b  = (bf16_t*)(ws + 145 * MB);    // 32 MiB (ends at 177 MiB)

    hipMemsetAsync(ws, 0, 256, stream);         // counts/cursor/offsets

    dim3 gp1(2 * ID / 64, HD / 64, NEXP);       // w13: K=HD, N=2*ID -> [n][k]
    precast_kernel<<<gp1, 256, 0, stream>>>(w13, w13b, HD, 2 * ID);
    dim3 gp2(HD / 64, ID / 64, NEXP);           // w2: K=ID, N=HD -> [n][k]
    precast_kernel<<<gp2, 256, 0, stream>>>(w2, w2b, ID, HD);

    router_kernel<<<NTOK, 256, 0, stream>>>(x, rw, xb, topk_idx, topk_w);
    count_kernel<<<NTOK / 256, 256, 0, stream>>>(topk_idx, counts);
    scan_kernel<<<1, 64, 0, stream>>>(counts, offsets, cursor, map256, map128);
    scatter_kernel<<<NTOK / 256, 256, 0, stream>>>(topk_idx, topk_w, cursor,
                                                   token_list, row_w, row_pos);

    dim3 g1(ID / 64, MAXT1);                    // 32 x 72 = 2304 blocks (8 | 2304)
    gemm1_kernel<<<g1, 512, 0, stream>>>(xb, w13b, offsets, counts, token_list,
                                         map256, hbuf);
    dim3 g2(HD / 128, MAXT2);                   // 8 x 136 = 1088 blocks (8 | 1088)
    gemm2_kernel<<<g2, 512, 0, stream>>>(hbuf, w2b, offsets, counts, row_w,
                                         map128, ybuf);
    combine_kernel<<<NTOK, 256, 0, stream>>>(ybuf, row_pos, out);
}

// Round 14
// 558.545 us; speedup vs baseline: 1.0627x; 1.0141x over previous
//
#include <hip/hip_runtime.h>
#include <hip/hip_bf16.h>
#include <math.h>

// Problem constants (AydinConfig: H=1024, I=2048, E=8, K=2; B=4, S=2048)
#define NEXP 8
#define HD 1024
#define ID 2048
#define NTOK 8192          // B*S
#define NROWS 16384        // NTOK * top_k

typedef __bf16 bf16_t;
typedef __bf16 bf16x8 __attribute__((ext_vector_type(8)));
typedef float f32x4 __attribute__((ext_vector_type(4)));

// MEASURED LEDGER (do not regress):
//  r5 atomicAdd epi +21; r6 gemm2 BN=64 +22 -> gemm2 = BN=128 + ybuf + combine.
//  r7 launch_bounds cap < need -> SPILL. Never cap below need.
//  r8 occ not binding; r9 swizzle conflicts->0; r10 LDS volume not binding;
//  r11 BK 32->64 gemm1 -12.5%; r12 XCD swizzle gemm1 -8us, gemm2 BK=128.
//  r13 3-slot counted-vmcnt ring on gemm1: REGRESSED (160->184us, FETCH
//    191->285MB — prefetch distance destroys cross-block L2 reuse of A-rows).
//    Ring attempts now 0/3; 2-phase + BK amortization + XCD locality wins.
//    BUT r13's gemm2 XCD swizzle gained ~24us (rest-of-pipe 406->382).
//  => r14: compose bests. gemm1 = r12 exact (160us). gemm2 = r13 exact.
#define BK1 64             // gemm1 K-step
#define BK2 128            // gemm2 K-step
#define MAXT1 72           // 256-row tiles: sum ceil(c/256) <= 71
#define MAXT2 136          // 128-row tiles: sum ceil(c/128) <= 135

// async global->LDS, 16B per lane. LDS dest must be wave-uniform base + lane*16.
__device__ __forceinline__ void gl16(const void* g, void* l) {
    __builtin_amdgcn_global_load_lds(
        (const __attribute__((address_space(1))) unsigned int*)g,
        (__attribute__((address_space(3))) unsigned int*)l, 16, 0, 0);
}

// ---------------------------------------------------------------- router ----
__global__ __launch_bounds__(256)
void router_kernel(const float* __restrict__ x, const float* __restrict__ rw,
                   bf16_t* __restrict__ xb, int* __restrict__ topk_idx,
                   float* __restrict__ topk_w)
{
    const int t = blockIdx.x;
    const int tid = threadIdx.x;
    const float4 xv = ((const float4*)(x + (size_t)t * HD))[tid];
    float acc[NEXP];
#pragma unroll
    for (int e = 0; e < NEXP; ++e) {
        const float4 w4 = ((const float4*)(rw + e * HD))[tid];
        acc[e] = xv.x * w4.x + xv.y * w4.y + xv.z * w4.z + xv.w * w4.w;
    }
    bf16_t tmp[4] = {(bf16_t)xv.x, (bf16_t)xv.y, (bf16_t)xv.z, (bf16_t)xv.w};
    *(uint2*)(xb + (size_t)t * HD + tid * 4) = *(const uint2*)tmp;

    __shared__ float red[4][NEXP];
    const int lane = tid & 63, wv = tid >> 6;
#pragma unroll
    for (int e = 0; e < NEXP; ++e) {
        float v = acc[e];
#pragma unroll
        for (int off = 32; off >= 1; off >>= 1) v += __shfl_down(v, off, 64);
        if (lane == 0) red[wv][e] = v;
    }
    __syncthreads();
    if (tid == 0) {
        float lg[NEXP], mx = -1e30f;
#pragma unroll
        for (int e = 0; e < NEXP; ++e) {
            lg[e] = red[0][e] + red[1][e] + red[2][e] + red[3][e];
            mx = fmaxf(mx, lg[e]);
        }
        float p[NEXP], s = 0.f;
#pragma unroll
        for (int e = 0; e < NEXP; ++e) { p[e] = __expf(lg[e] - mx); s += p[e]; }
        const float inv = 1.f / s;
#pragma unroll
        for (int e = 0; e < NEXP; ++e) p[e] *= inv;
        int i0 = 0; float p0 = p[0];
#pragma unroll
        for (int e = 1; e < NEXP; ++e) if (p[e] > p0) { p0 = p[e]; i0 = e; }
        int i1 = -1; float p1 = -1.f;
#pragma unroll
        for (int e = 0; e < NEXP; ++e) if (e != i0 && p[e] > p1) { p1 = p[e]; i1 = e; }
        const float d = 1.f / (p0 + p1 + 1e-6f);
        topk_idx[t * 2 + 0] = i0; topk_idx[t * 2 + 1] = i1;
        topk_w[t * 2 + 0] = p0 * d; topk_w[t * 2 + 1] = p1 * d;
    }
}

// ----------------------------------------------------------------- count ----
__global__ __launch_bounds__(256)
void count_kernel(const int* __restrict__ topk_idx, int* __restrict__ counts)
{
    __shared__ int lc[NEXP];
    const int tid = threadIdx.x;
    if (tid < NEXP) lc[tid] = 0;
    __syncthreads();
    const int t = blockIdx.x * 256 + tid;
    atomicAdd(&lc[topk_idx[t * 2 + 0]], 1);
    atomicAdd(&lc[topk_idx[t * 2 + 1]], 1);
    __syncthreads();
    if (tid < NEXP) atomicAdd(&counts[tid], lc[tid]);
}

// ------------------------------------------------------------------ scan ----
__global__ void scan_kernel(const int* __restrict__ counts, int* __restrict__ offsets,
                            int* __restrict__ cursor,
                            unsigned* __restrict__ map256, unsigned* __restrict__ map128)
{
    __shared__ int tb2[NEXP + 1], tb1[NEXP + 1];
    if (threadIdx.x == 0) {
        int s = 0, t2 = 0, t1 = 0;
        for (int e = 0; e < NEXP; ++e) {
            offsets[e] = s; cursor[e] = s; s += counts[e];
            tb2[e] = t2; t2 += (counts[e] + 255) >> 8;
            tb1[e] = t1; t1 += (counts[e] + 127) >> 7;
        }
        tb2[NEXP] = t2; tb1[NEXP] = t1;
    }
    __syncthreads();
    for (int i = threadIdx.x; i < MAXT1; i += 64) {
        unsigned v = 0xFFFFFFFFu;
#pragma unroll
        for (int e = 0; e < NEXP; ++e)
            if (i >= tb2[e] && i < tb2[e + 1]) v = ((unsigned)e << 16) | (unsigned)(i - tb2[e]);
        map256[i] = v;
    }
    for (int i = threadIdx.x; i < MAXT2; i += 64) {
        unsigned v = 0xFFFFFFFFu;
#pragma unroll
        for (int e = 0; e < NEXP; ++e)
            if (i >= tb1[e] && i < tb1[e + 1]) v = ((unsigned)e << 16) | (unsigned)(i - tb1[e]);
        map128[i] = v;
    }
}

// --------------------------------------------------------------- scatter ----
__global__ __launch_bounds__(256)
void scatter_kernel(const int* __restrict__ topk_idx, const float* __restrict__ topk_w,
                    int* __restrict__ cursor, int* __restrict__ token_list,
                    float* __restrict__ row_w, int* __restrict__ row_pos)
{
    __shared__ int lc[NEXP], gbase[NEXP];
    const int tid = threadIdx.x;
    if (tid < NEXP) lc[tid] = 0;
    __syncthreads();
    const int t = blockIdx.x * 256 + tid;
    const int e0 = topk_idx[t * 2 + 0], e1 = topk_idx[t * 2 + 1];
    const int lp0 = atomicAdd(&lc[e0], 1);
    const int lp1 = atomicAdd(&lc[e1], 1);
    __syncthreads();
    if (tid < NEXP) gbase[tid] = atomicAdd(&cursor[tid], lc[tid]);
    __syncthreads();
    const int p0 = gbase[e0] + lp0, p1 = gbase[e1] + lp1;
    token_list[p0] = t; row_w[p0] = topk_w[t * 2 + 0]; row_pos[t * 2 + 0] = p0;
    token_list[p1] = t; row_w[p1] = topk_w[t * 2 + 1]; row_pos[t * 2 + 1] = p1;
}

// -------------------------------------------------------- precast weights ----
__global__ __launch_bounds__(256)
void precast_kernel(const float* __restrict__ src, bf16_t* __restrict__ dst,
                    int K, int N)
{
    const int e = blockIdx.z;
    src += (size_t)e * K * N;
    dst += (size_t)e * K * N;
    const int n0 = blockIdx.x * 64, k0 = blockIdx.y * 64;
    __shared__ float tile[64][65];
    const int tid = threadIdx.x;
    const int tx = (tid & 15) * 4, ty = tid >> 4;
#pragma unroll
    for (int p = 0; p < 4; ++p) {
        const float4 v = *(const float4*)(src + (size_t)(k0 + ty + p * 16) * N + n0 + tx);
        tile[ty + p * 16][tx + 0] = v.x;
        tile[ty + p * 16][tx + 1] = v.y;
        tile[ty + p * 16][tx + 2] = v.z;
        tile[ty + p * 16][tx + 3] = v.w;
    }
    __syncthreads();
    const int n = tid >> 2, kc = (tid & 3) * 16;
    bf16_t outv[16];
#pragma unroll
    for (int j = 0; j < 16; ++j) outv[j] = (bf16_t)tile[kc + j][n];
    bf16_t* d = dst + (size_t)(n0 + n) * K + k0 + kc;
    *(uint4*)d = *(uint4*)outv;
    *(uint4*)(d + 8) = *((uint4*)outv + 1);
}

// ------------------------------------------------- grouped GEMM1 + SwiGLU ----
// r12 EXACT (measured 160us): 256x64 tile, 512 thr, BK=64, 2-barrier loop,
// 64-col involution swizzle (phys chunk = logical ^ (row&7), both sides),
// XCD id swizzle (2304 = 8 x 288, bijective).
__global__ __launch_bounds__(512)
void gemm1_kernel(const bf16_t* __restrict__ xb, const bf16_t* __restrict__ w13b,
                  const int* __restrict__ offsets, const int* __restrict__ counts,
                  const int* __restrict__ token_list,
                  const unsigned* __restrict__ tile_map, bf16_t* __restrict__ hbuf)
{
    unsigned id = blockIdx.y * 32u + blockIdx.x;
    id = (id & 7u) * 288u + (id >> 3);       // bijective: 2304 = 8 * 288
    const unsigned tm = tile_map[id >> 5];
    if (tm == 0xFFFFFFFFu) return;
    const int e = (int)(tm >> 16), mt = (int)(tm & 0xFFFFu);
    const int rows = counts[e];
    const int row_base = offsets[e];
    const int r0 = mt * 256;
    const int n0 = (int)(id & 31u) * 64;     // swiglu-col tile (64 gate + 64 up)

    __shared__ alignas(16) bf16_t As[256][64];   // 32 KiB
    __shared__ alignas(16) bf16_t Bg[64][64];    // 8 KiB
    __shared__ alignas(16) bf16_t Bu[64][64];    // 8 KiB

    const int tid = threadIdx.x;
    const int lane = tid & 63;
    const int wv = tid >> 6;                 // 0..7
    const int wr = wv >> 1, wc = wv & 1;     // wave: rows [wr*64,+64), cols [wc*32,+32)
    const int ln15 = lane & 15, q = lane >> 4;
    const int x7 = ln15 & 7;                 // row&7 for every fragment-read row
    const int c0 = ((q ^ x7)) * 8;           // kk=0 chunk byte-elems
    const int c1 = c0 ^ 32;                  // kk=1: (q|4)^x7 = (q^x7)^4 -> +-32 elems

    const int srow = tid >> 3;               // 0..63
    const int scol = ((tid & 7) ^ ((tid >> 3) & 7)) * 8;   // p*64 doesn't affect &7
    const bf16_t* ap[4];
#pragma unroll
    for (int p = 0; p < 4; ++p) {
        int gr = row_base + r0 + p * 64 + srow;
        if (gr > NROWS - 1) gr = NROWS - 1;
        ap[p] = xb + (size_t)token_list[gr] * HD + scol;
    }
    const bf16_t* wb = w13b + (size_t)e * HD * (2 * ID);
    const bf16_t* bgp = wb + (size_t)(n0 + srow) * HD + scol;
    const bf16_t* bup = wb + (size_t)(ID + n0 + srow) * HD + scol;
    bf16_t* const d_bg = &Bg[0][0] + tid * 8;
    bf16_t* const d_bu = &Bu[0][0] + tid * 8;

    f32x4 accG[4][2], accU[4][2];
#pragma unroll
    for (int i = 0; i < 4; ++i)
#pragma unroll
        for (int j = 0; j < 2; ++j)
#pragma unroll
            for (int c = 0; c < 4; ++c) { accG[i][j][c] = 0.f; accU[i][j][c] = 0.f; }

    for (int k0 = 0; k0 < HD; k0 += BK1) {
#pragma unroll
        for (int p = 0; p < 4; ++p) {
            gl16(ap[p], &As[0][0] + (p * 512 + tid) * 8);
            ap[p] += BK1;
        }
        gl16(bgp, d_bg); gl16(bup, d_bu);
        bgp += BK1; bup += BK1;
        __syncthreads();

#pragma unroll
        for (int kk = 0; kk < 2; ++kk) {
            const int cc = kk ? c1 : c0;
            bf16x8 af[4], bgf[2], buf_[2];
#pragma unroll
            for (int i = 0; i < 4; ++i)
                af[i] = *(const bf16x8*)&As[wr * 64 + i * 16 + ln15][cc];
#pragma unroll
            for (int j = 0; j < 2; ++j) {
                bgf[j]  = *(const bf16x8*)&Bg[wc * 32 + j * 16 + ln15][cc];
                buf_[j] = *(const bf16x8*)&Bu[wc * 32 + j * 16 + ln15][cc];
            }
#pragma unroll
            for (int i = 0; i < 4; ++i)
#pragma unroll
                for (int j = 0; j < 2; ++j) {
                    accG[i][j] = __builtin_amdgcn_mfma_f32_16x16x32_bf16(af[i], bgf[j], accG[i][j], 0, 0, 0);
                    accU[i][j] = __builtin_amdgcn_mfma_f32_16x16x32_bf16(af[i], buf_[j], accU[i][j], 0, 0, 0);
                }
        }
        __syncthreads();
    }

    // epilogue: SwiGLU in fp32, store bf16. C/D: col=lane&15, row=q*4+reg
#pragma unroll
    for (int i = 0; i < 4; ++i) {
#pragma unroll
        for (int reg = 0; reg < 4; ++reg) {
            const int rr = wr * 64 + i * 16 + q * 4 + reg;
            if (r0 + rr < rows) {
                bf16_t* dst = hbuf + (size_t)(row_base + r0 + rr) * ID + n0 + wc * 32 + ln15;
#pragma unroll
                for (int j = 0; j < 2; ++j) {
                    const float g = accG[i][j][reg], u = accU[i][j][reg];
                    dst[j * 16] = (bf16_t)((g / (1.f + __expf(-g))) * u);
                }
            }
        }
    }
}

// --------------------------------------------------------- grouped GEMM2 ----
// r13 EXACT: 128x128 tile, BK=128 (16 steps), 128-col swizzle, XCD id swizzle
// (1088 = 8 x 136, bijective), ybuf plain stores + combine.
__global__ __launch_bounds__(512)
void gemm2_kernel(const bf16_t* __restrict__ hbuf, const bf16_t* __restrict__ w2b,
                  const int* __restrict__ offsets, const int* __restrict__ counts,
                  const float* __restrict__ row_w,
                  const unsigned* __restrict__ tile_map, float* __restrict__ ybuf)
{
    unsigned id = blockIdx.y * 8u + blockIdx.x;
    id = (id & 7u) * 136u + (id >> 3);       // bijective: 1088 = 8 * 136
    const unsigned tm = tile_map[id >> 3];
    if (tm == 0xFFFFFFFFu) return;
    const int e = (int)(tm >> 16), mt = (int)(tm & 0xFFFFu);
    const int rows = counts[e];
    const int row_base = offsets[e];
    const int r0 = mt * 128;
    const int n0 = (int)(id & 7u) * 128;

    __shared__ alignas(16) bf16_t As[128][128];  // 32 KiB
    __shared__ alignas(16) bf16_t Bs[128][128];  // 32 KiB
    __shared__ float rww_s[128];

    const int tid = threadIdx.x;
    if (tid < 128) {
        int gr = row_base + r0 + tid; if (gr > NROWS - 1) gr = NROWS - 1;
        rww_s[tid] = row_w[gr];
    }
    const int lane = tid & 63;
    const int wv = tid >> 6;
    const int wr = wv >> 1, wc = wv & 1;     // wave: rows [wr*32,+32), cols [wc*64,+64)
    const int ln15 = lane & 15, q = lane >> 4;

    const int srow = tid >> 4;               // 0..31 (row within 32-row stripe)
    const int scol = ((tid & 15) ^ ((tid >> 4) & 15)) * 8;
    const bf16_t* ap[4];
    const bf16_t* bp[4];
    const bf16_t* w2e = w2b + (size_t)e * ID * HD;
#pragma unroll
    for (int p = 0; p < 4; ++p) {
        int gr = row_base + r0 + p * 32 + srow;
        if (gr > NROWS - 1) gr = NROWS - 1;
        ap[p] = hbuf + (size_t)gr * ID + scol;
        bp[p] = w2e + (size_t)(n0 + p * 32 + srow) * ID + scol;
    }

    f32x4 acc[2][4];
#pragma unroll
    for (int i = 0; i < 2; ++i)
#pragma unroll
        for (int j = 0; j < 4; ++j)
#pragma unroll
            for (int c = 0; c < 4; ++c) acc[i][j][c] = 0.f;

    for (int k0 = 0; k0 < ID; k0 += BK2) {
#pragma unroll
        for (int p = 0; p < 4; ++p) {
            gl16(ap[p], &As[0][0] + (p * 512 + tid) * 8);
            gl16(bp[p], &Bs[0][0] + (p * 512 + tid) * 8);
            ap[p] += BK2; bp[p] += BK2;
        }
        __syncthreads();

#pragma unroll
        for (int kk = 0; kk < 4; ++kk) {
            const int cc = ((kk * 4 + q) ^ ln15) * 8;
            bf16x8 af[2], bf_[4];
#pragma unroll
            for (int i = 0; i < 2; ++i)
                af[i] = *(const bf16x8*)&As[wr * 32 + i * 16 + ln15][cc];
#pragma unroll
            for (int j = 0; j < 4; ++j)
                bf_[j] = *(const bf16x8*)&Bs[wc * 64 + j * 16 + ln15][cc];
#pragma unroll
            for (int i = 0; i < 2; ++i)
#pragma unroll
                for (int j = 0; j < 4; ++j)
                    acc[i][j] = __builtin_amdgcn_mfma_f32_16x16x32_bf16(af[i], bf_[j], acc[i][j], 0, 0, 0);
        }
        __syncthreads();
    }

    // epilogue: weighted plain stores into dense per-row buffer
#pragma unroll
    for (int i = 0; i < 2; ++i) {
#pragma unroll
        for (int reg = 0; reg < 4; ++reg) {
            const int rr = wr * 32 + i * 16 + q * 4 + reg;
            if (r0 + rr < rows) {
                const float w = rww_s[rr];
                float* dst = ybuf + (size_t)(row_base + r0 + rr) * HD + n0 + wc * 64 + ln15;
#pragma unroll
                for (int j = 0; j < 4; ++j)
                    dst[j * 16] = acc[i][j][reg] * w;
            }
        }
    }
}

// --------------------------------------------------------------- combine ----
__global__ __launch_bounds__(256)
void combine_kernel(const float* __restrict__ ybuf, const int* __restrict__ row_pos,
                    float* __restrict__ out)
{
    const int t = blockIdx.x;
    const int p0 = row_pos[t * 2 + 0], p1 = row_pos[t * 2 + 1];
    const float4 a = ((const float4*)(ybuf + (size_t)p0 * HD))[threadIdx.x];
    const float4 b = ((const float4*)(ybuf + (size_t)p1 * HD))[threadIdx.x];
    float4 o; o.x = a.x + b.x; o.y = a.y + b.y; o.z = a.z + b.z; o.w = a.w + b.w;
    ((float4*)(out + (size_t)t * HD))[threadIdx.x] = o;
}

// ---------------------------------------------------------------- launch ----
extern "C" void kernel_launch(void* const* d_in, const int* in_sizes, int n_in,
                              void* d_out, int out_size, void* d_ws, size_t ws_size,
                              hipStream_t stream) {
    const float* x   = (const float*)d_in[0];   // (4,2048,1024)
    const float* rw  = (const float*)d_in[1];   // (8,1024)
    const float* w13 = (const float*)d_in[2];   // (8,1024,4096)
    const float* w2  = (const float*)d_in[3];   // (8,2048,1024)
    float* out = (float*)d_out;                 // (4,2048,1024) fp32

    char* ws = (char*)d_ws;
    int*      counts     = (int*)(ws + 0);
    int*      cursor     = (int*)(ws + 64);
    int*      offsets    = (int*)(ws + 128);
    int*      topk_idx   = (int*)(ws + 256);
    float*    topk_w     = (float*)(ws + 256 + 1 * 65536);
    int*      token_list = (int*)(ws + 256 + 2 * 65536);
    float*    row_w      = (float*)(ws + 256 + 3 * 65536);
    int*      row_pos    = (int*)(ws + 256 + 4 * 65536);
    unsigned* map256     = (unsigned*)(ws + 256 + 5 * 65536);
    unsigned* map128     = (unsigned*)(ws + 256 + 6 * 65536);
    const size_t MB = 1024 * 1024;
    bf16_t* xb   = (bf16_t*)(ws + 1 * MB);      // 16 MiB
    bf16_t* hbuf = (bf16_t*)(ws + 17 * MB);     // 64 MiB
    bf16_t* w13b = (bf16_t*)(ws + 81 * MB);     // 64 MiB (dead after gemm1)
    float*  ybuf = (float*)(ws + 81 * MB);      // 64 MiB fp32, ALIASES w13b
                                                // (stream-ordered: gemm1 reads,
                                                //  then gemm2 overwrites)
    bf16_t* w2b  = (bf16_t*)(ws + 145 * MB);    // 32 MiB (ends at 177 MiB)

    hipMemsetAsync(ws, 0, 256, stream);         // counts/cursor/offsets

    dim3 gp1(2 * ID / 64, HD / 64, NEXP);       // w13: K=HD, N=2*ID -> [n][k]
    precast_kernel<<<gp1, 256, 0, stream>>>(w13, w13b, HD, 2 * ID);
    dim3 gp2(HD / 64, ID / 64, NEXP);           // w2: K=ID, N=HD -> [n][k]
    precast_kernel<<<gp2, 256, 0, stream>>>(w2, w2b, ID, HD);

    router_kernel<<<NTOK, 256, 0, stream>>>(x, rw, xb, topk_idx, topk_w);
    count_kernel<<<NTOK / 256, 256, 0, stream>>>(topk_idx, counts);
    scan_kernel<<<1, 64, 0, stream>>>(counts, offsets, cursor, map256, map128);
    scatter_kernel<<<NTOK / 256, 256, 0, stream>>>(topk_idx, topk_w, cursor,
                                                   token_list, row_w, row_pos);

    dim3 g1(ID / 64, MAXT1);                    // 32 x 72 = 2304 blocks (8 | 2304)
    gemm1_kernel<<<g1, 512, 0, stream>>>(xb, w13b, offsets, counts, token_list,
                                         map256, hbuf);
    dim3 g2(HD / 128, MAXT2);                   // 8 x 136 = 1088 blocks (8 | 1088)
    gemm2_kernel<<<g2, 512, 0, stream>>>(hbuf, w2b, offsets, counts, row_w,
                                         map128, ybuf);
    combine_kernel<<<NTOK, 256, 0, stream>>>(ybuf, row_pos, out);
}

// Round 15
// 548.145 us; speedup vs baseline: 1.0829x; 1.0190x over previous
//
#include <hip/hip_runtime.h>
#include <hip/hip_bf16.h>
#include <math.h>

// Problem constants (AydinConfig: H=1024, I=2048, E=8, K=2; B=4, S=2048)
#define NEXP 8
#define HD 1024
#define ID 2048
#define NTOK 8192          // B*S
#define NROWS 16384        // NTOK * top_k

typedef __bf16 bf16_t;
typedef __bf16 bf16x8 __attribute__((ext_vector_type(8)));
typedef float f32x4 __attribute__((ext_vector_type(4)));

// MEASURED LEDGER (do not regress):
//  r5 atomicAdd epi +21; r6 gemm2 BN=64 +22 -> gemm2 = BN=128 + ybuf + combine.
//  r7 launch_bounds cap < need -> SPILL. Never cap below need.
//  r8 occ not binding; r9 swizzle conflicts->0; r10 LDS volume not binding;
//  r11 BK 32->64 gemm1 -12.5%; r12 XCD swizzle -8us + gemm2 BK=128;
//  r13 counted-vmcnt ring REGRESSED (prefetch distance kills L2 reuse,
//    FETCH 191->285MB) — pipelining attempts 0/3, 2-phase + BK + XCD wins;
//  r14 compose bests: gemm1=r12 (163us), gemm2=r13 -> total 558.5 (best).
//  GEMMs at 2-phase structural plateau (~843 TF eff). r15: non-GEMM harvest —
//  router & combine to wave-per-token (no barriers/LDS/serial-tail waste).
#define BK1 64             // gemm1 K-step
#define BK2 128            // gemm2 K-step
#define MAXT1 72           // 256-row tiles: sum ceil(c/256) <= 71
#define MAXT2 136          // 128-row tiles: sum ceil(c/128) <= 135

// async global->LDS, 16B per lane. LDS dest must be wave-uniform base + lane*16.
__device__ __forceinline__ void gl16(const void* g, void* l) {
    __builtin_amdgcn_global_load_lds(
        (const __attribute__((address_space(1))) unsigned int*)g,
        (__attribute__((address_space(3))) unsigned int*)l, 16, 0, 0);
}

// ---------------------------------------------------------------- router ----
// wave-per-token: 4 tokens/block, all-register reduce (no LDS, no barriers).
// Lane l covers elements (i*64+l)*4 .. +3, i=0..3 (coalesced float4 loads).
__global__ __launch_bounds__(256)
void router_kernel(const float* __restrict__ x, const float* __restrict__ rw,
                   bf16_t* __restrict__ xb, int* __restrict__ topk_idx,
                   float* __restrict__ topk_w)
{
    const int wv = threadIdx.x >> 6, lane = threadIdx.x & 63;
    const int t = blockIdx.x * 4 + wv;
    const float4* xr = (const float4*)(x + (size_t)t * HD);
    float4 xv[4];
#pragma unroll
    for (int i = 0; i < 4; ++i) xv[i] = xr[i * 64 + lane];

    float acc[NEXP];
#pragma unroll
    for (int e = 0; e < NEXP; ++e) {
        const float4* wr4 = (const float4*)(rw + e * HD);
        float s = 0.f;
#pragma unroll
        for (int i = 0; i < 4; ++i) {
            const float4 w4 = wr4[i * 64 + lane];
            s += xv[i].x * w4.x + xv[i].y * w4.y + xv[i].z * w4.z + xv[i].w * w4.w;
        }
        acc[e] = s;
    }
    // fused fp32 -> bf16 cast of x (same coalesced pattern)
    bf16_t* xbr = xb + (size_t)t * HD;
#pragma unroll
    for (int i = 0; i < 4; ++i) {
        bf16_t tmp[4] = {(bf16_t)xv[i].x, (bf16_t)xv[i].y,
                         (bf16_t)xv[i].z, (bf16_t)xv[i].w};
        *(uint2*)(xbr + (i * 64 + lane) * 4) = *(const uint2*)tmp;
    }
    // 64-lane shuffle reduce per expert
#pragma unroll
    for (int e = 0; e < NEXP; ++e) {
#pragma unroll
        for (int off = 32; off >= 1; off >>= 1)
            acc[e] += __shfl_down(acc[e], off, 64);
    }
    if (lane == 0) {
        float mx = -1e30f;
#pragma unroll
        for (int e = 0; e < NEXP; ++e) mx = fmaxf(mx, acc[e]);
        float p[NEXP], s = 0.f;
#pragma unroll
        for (int e = 0; e < NEXP; ++e) { p[e] = __expf(acc[e] - mx); s += p[e]; }
        const float inv = 1.f / s;
#pragma unroll
        for (int e = 0; e < NEXP; ++e) p[e] *= inv;
        int i0 = 0; float p0 = p[0];
#pragma unroll
        for (int e = 1; e < NEXP; ++e) if (p[e] > p0) { p0 = p[e]; i0 = e; }
        int i1 = -1; float p1 = -1.f;
#pragma unroll
        for (int e = 0; e < NEXP; ++e) if (e != i0 && p[e] > p1) { p1 = p[e]; i1 = e; }
        const float d = 1.f / (p0 + p1 + 1e-6f);
        topk_idx[t * 2 + 0] = i0; topk_idx[t * 2 + 1] = i1;
        topk_w[t * 2 + 0] = p0 * d; topk_w[t * 2 + 1] = p1 * d;
    }
}

// ----------------------------------------------------------------- count ----
__global__ __launch_bounds__(256)
void count_kernel(const int* __restrict__ topk_idx, int* __restrict__ counts)
{
    __shared__ int lc[NEXP];
    const int tid = threadIdx.x;
    if (tid < NEXP) lc[tid] = 0;
    __syncthreads();
    const int t = blockIdx.x * 256 + tid;
    atomicAdd(&lc[topk_idx[t * 2 + 0]], 1);
    atomicAdd(&lc[topk_idx[t * 2 + 1]], 1);
    __syncthreads();
    if (tid < NEXP) atomicAdd(&counts[tid], lc[tid]);
}

// ------------------------------------------------------------------ scan ----
__global__ void scan_kernel(const int* __restrict__ counts, int* __restrict__ offsets,
                            int* __restrict__ cursor,
                            unsigned* __restrict__ map256, unsigned* __restrict__ map128)
{
    __shared__ int tb2[NEXP + 1], tb1[NEXP + 1];
    if (threadIdx.x == 0) {
        int s = 0, t2 = 0, t1 = 0;
        for (int e = 0; e < NEXP; ++e) {
            offsets[e] = s; cursor[e] = s; s += counts[e];
            tb2[e] = t2; t2 += (counts[e] + 255) >> 8;
            tb1[e] = t1; t1 += (counts[e] + 127) >> 7;
        }
        tb2[NEXP] = t2; tb1[NEXP] = t1;
    }
    __syncthreads();
    for (int i = threadIdx.x; i < MAXT1; i += 64) {
        unsigned v = 0xFFFFFFFFu;
#pragma unroll
        for (int e = 0; e < NEXP; ++e)
            if (i >= tb2[e] && i < tb2[e + 1]) v = ((unsigned)e << 16) | (unsigned)(i - tb2[e]);
        map256[i] = v;
    }
    for (int i = threadIdx.x; i < MAXT2; i += 64) {
        unsigned v = 0xFFFFFFFFu;
#pragma unroll
        for (int e = 0; e < NEXP; ++e)
            if (i >= tb1[e] && i < tb1[e + 1]) v = ((unsigned)e << 16) | (unsigned)(i - tb1[e]);
        map128[i] = v;
    }
}

// --------------------------------------------------------------- scatter ----
__global__ __launch_bounds__(256)
void scatter_kernel(const int* __restrict__ topk_idx, const float* __restrict__ topk_w,
                    int* __restrict__ cursor, int* __restrict__ token_list,
                    float* __restrict__ row_w, int* __restrict__ row_pos)
{
    __shared__ int lc[NEXP], gbase[NEXP];
    const int tid = threadIdx.x;
    if (tid < NEXP) lc[tid] = 0;
    __syncthreads();
    const int t = blockIdx.x * 256 + tid;
    const int e0 = topk_idx[t * 2 + 0], e1 = topk_idx[t * 2 + 1];
    const int lp0 = atomicAdd(&lc[e0], 1);
    const int lp1 = atomicAdd(&lc[e1], 1);
    __syncthreads();
    if (tid < NEXP) gbase[tid] = atomicAdd(&cursor[tid], lc[tid]);
    __syncthreads();
    const int p0 = gbase[e0] + lp0, p1 = gbase[e1] + lp1;
    token_list[p0] = t; row_w[p0] = topk_w[t * 2 + 0]; row_pos[t * 2 + 0] = p0;
    token_list[p1] = t; row_w[p1] = topk_w[t * 2 + 1]; row_pos[t * 2 + 1] = p1;
}

// -------------------------------------------------------- precast weights ----
__global__ __launch_bounds__(256)
void precast_kernel(const float* __restrict__ src, bf16_t* __restrict__ dst,
                    int K, int N)
{
    const int e = blockIdx.z;
    src += (size_t)e * K * N;
    dst += (size_t)e * K * N;
    const int n0 = blockIdx.x * 64, k0 = blockIdx.y * 64;
    __shared__ float tile[64][65];
    const int tid = threadIdx.x;
    const int tx = (tid & 15) * 4, ty = tid >> 4;
#pragma unroll
    for (int p = 0; p < 4; ++p) {
        const float4 v = *(const float4*)(src + (size_t)(k0 + ty + p * 16) * N + n0 + tx);
        tile[ty + p * 16][tx + 0] = v.x;
        tile[ty + p * 16][tx + 1] = v.y;
        tile[ty + p * 16][tx + 2] = v.z;
        tile[ty + p * 16][tx + 3] = v.w;
    }
    __syncthreads();
    const int n = tid >> 2, kc = (tid & 3) * 16;
    bf16_t outv[16];
#pragma unroll
    for (int j = 0; j < 16; ++j) outv[j] = (bf16_t)tile[kc + j][n];
    bf16_t* d = dst + (size_t)(n0 + n) * K + k0 + kc;
    *(uint4*)d = *(uint4*)outv;
    *(uint4*)(d + 8) = *((uint4*)outv + 1);
}

// ------------------------------------------------- grouped GEMM1 + SwiGLU ----
// r12/r14 EXACT (measured 163us): 256x64 tile, 512 thr, BK=64, 2-barrier loop,
// 64-col involution swizzle (phys chunk = logical ^ (row&7), both sides),
// XCD id swizzle (2304 = 8 x 288, bijective).
__global__ __launch_bounds__(512)
void gemm1_kernel(const bf16_t* __restrict__ xb, const bf16_t* __restrict__ w13b,
                  const int* __restrict__ offsets, const int* __restrict__ counts,
                  const int* __restrict__ token_list,
                  const unsigned* __restrict__ tile_map, bf16_t* __restrict__ hbuf)
{
    unsigned id = blockIdx.y * 32u + blockIdx.x;
    id = (id & 7u) * 288u + (id >> 3);       // bijective: 2304 = 8 * 288
    const unsigned tm = tile_map[id >> 5];
    if (tm == 0xFFFFFFFFu) return;
    const int e = (int)(tm >> 16), mt = (int)(tm & 0xFFFFu);
    const int rows = counts[e];
    const int row_base = offsets[e];
    const int r0 = mt * 256;
    const int n0 = (int)(id & 31u) * 64;     // swiglu-col tile (64 gate + 64 up)

    __shared__ alignas(16) bf16_t As[256][64];   // 32 KiB
    __shared__ alignas(16) bf16_t Bg[64][64];    // 8 KiB
    __shared__ alignas(16) bf16_t Bu[64][64];    // 8 KiB

    const int tid = threadIdx.x;
    const int lane = tid & 63;
    const int wv = tid >> 6;                 // 0..7
    const int wr = wv >> 1, wc = wv & 1;     // wave: rows [wr*64,+64), cols [wc*32,+32)
    const int ln15 = lane & 15, q = lane >> 4;
    const int x7 = ln15 & 7;                 // row&7 for every fragment-read row
    const int c0 = ((q ^ x7)) * 8;           // kk=0 chunk byte-elems
    const int c1 = c0 ^ 32;                  // kk=1: (q|4)^x7 = (q^x7)^4 -> +-32 elems

    const int srow = tid >> 3;               // 0..63
    const int scol = ((tid & 7) ^ ((tid >> 3) & 7)) * 8;   // p*64 doesn't affect &7
    const bf16_t* ap[4];
#pragma unroll
    for (int p = 0; p < 4; ++p) {
        int gr = row_base + r0 + p * 64 + srow;
        if (gr > NROWS - 1) gr = NROWS - 1;
        ap[p] = xb + (size_t)token_list[gr] * HD + scol;
    }
    const bf16_t* wb = w13b + (size_t)e * HD * (2 * ID);
    const bf16_t* bgp = wb + (size_t)(n0 + srow) * HD + scol;
    const bf16_t* bup = wb + (size_t)(ID + n0 + srow) * HD + scol;
    bf16_t* const d_bg = &Bg[0][0] + tid * 8;
    bf16_t* const d_bu = &Bu[0][0] + tid * 8;

    f32x4 accG[4][2], accU[4][2];
#pragma unroll
    for (int i = 0; i < 4; ++i)
#pragma unroll
        for (int j = 0; j < 2; ++j)
#pragma unroll
            for (int c = 0; c < 4; ++c) { accG[i][j][c] = 0.f; accU[i][j][c] = 0.f; }

    for (int k0 = 0; k0 < HD; k0 += BK1) {
#pragma unroll
        for (int p = 0; p < 4; ++p) {
            gl16(ap[p], &As[0][0] + (p * 512 + tid) * 8);
            ap[p] += BK1;
        }
        gl16(bgp, d_bg); gl16(bup, d_bu);
        bgp += BK1; bup += BK1;
        __syncthreads();

#pragma unroll
        for (int kk = 0; kk < 2; ++kk) {
            const int cc = kk ? c1 : c0;
            bf16x8 af[4], bgf[2], buf_[2];
#pragma unroll
            for (int i = 0; i < 4; ++i)
                af[i] = *(const bf16x8*)&As[wr * 64 + i * 16 + ln15][cc];
#pragma unroll
            for (int j = 0; j < 2; ++j) {
                bgf[j]  = *(const bf16x8*)&Bg[wc * 32 + j * 16 + ln15][cc];
                buf_[j] = *(const bf16x8*)&Bu[wc * 32 + j * 16 + ln15][cc];
            }
#pragma unroll
            for (int i = 0; i < 4; ++i)
#pragma unroll
                for (int j = 0; j < 2; ++j) {
                    accG[i][j] = __builtin_amdgcn_mfma_f32_16x16x32_bf16(af[i], bgf[j], accG[i][j], 0, 0, 0);
                    accU[i][j] = __builtin_amdgcn_mfma_f32_16x16x32_bf16(af[i], buf_[j], accU[i][j], 0, 0, 0);
                }
        }
        __syncthreads();
    }

    // epilogue: SwiGLU in fp32, store bf16. C/D: col=lane&15, row=q*4+reg
#pragma unroll
    for (int i = 0; i < 4; ++i) {
#pragma unroll
        for (int reg = 0; reg < 4; ++reg) {
            const int rr = wr * 64 + i * 16 + q * 4 + reg;
            if (r0 + rr < rows) {
                bf16_t* dst = hbuf + (size_t)(row_base + r0 + rr) * ID + n0 + wc * 32 + ln15;
#pragma unroll
                for (int j = 0; j < 2; ++j) {
                    const float g = accG[i][j][reg], u = accU[i][j][reg];
                    dst[j * 16] = (bf16_t)((g / (1.f + __expf(-g))) * u);
                }
            }
        }
    }
}

// --------------------------------------------------------- grouped GEMM2 ----
// r13/r14 EXACT: 128x128 tile, BK=128 (16 steps), 128-col swizzle, XCD id
// swizzle (1088 = 8 x 136, bijective), ybuf plain stores + combine.
__global__ __launch_bounds__(512)
void gemm2_kernel(const bf16_t* __restrict__ hbuf, const bf16_t* __restrict__ w2b,
                  const int* __restrict__ offsets, const int* __restrict__ counts,
                  const float* __restrict__ row_w,
                  const unsigned* __restrict__ tile_map, float* __restrict__ ybuf)
{
    unsigned id = blockIdx.y * 8u + blockIdx.x;
    id = (id & 7u) * 136u + (id >> 3);       // bijective: 1088 = 8 * 136
    const unsigned tm = tile_map[id >> 3];
    if (tm == 0xFFFFFFFFu) return;
    const int e = (int)(tm >> 16), mt = (int)(tm & 0xFFFFu);
    const int rows = counts[e];
    const int row_base = offsets[e];
    const int r0 = mt * 128;
    const int n0 = (int)(id & 7u) * 128;

    __shared__ alignas(16) bf16_t As[128][128];  // 32 KiB
    __shared__ alignas(16) bf16_t Bs[128][128];  // 32 KiB
    __shared__ float rww_s[128];

    const int tid = threadIdx.x;
    if (tid < 128) {
        int gr = row_base + r0 + tid; if (gr > NROWS - 1) gr = NROWS - 1;
        rww_s[tid] = row_w[gr];
    }
    const int lane = tid & 63;
    const int wv = tid >> 6;
    const int wr = wv >> 1, wc = wv & 1;     // wave: rows [wr*32,+32), cols [wc*64,+64)
    const int ln15 = lane & 15, q = lane >> 4;

    const int srow = tid >> 4;               // 0..31 (row within 32-row stripe)
    const int scol = ((tid & 15) ^ ((tid >> 4) & 15)) * 8;
    const bf16_t* ap[4];
    const bf16_t* bp[4];
    const bf16_t* w2e = w2b + (size_t)e * ID * HD;
#pragma unroll
    for (int p = 0; p < 4; ++p) {
        int gr = row_base + r0 + p * 32 + srow;
        if (gr > NROWS - 1) gr = NROWS - 1;
        ap[p] = hbuf + (size_t)gr * ID + scol;
        bp[p] = w2e + (size_t)(n0 + p * 32 + srow) * ID + scol;
    }

    f32x4 acc[2][4];
#pragma unroll
    for (int i = 0; i < 2; ++i)
#pragma unroll
        for (int j = 0; j < 4; ++j)
#pragma unroll
            for (int c = 0; c < 4; ++c) acc[i][j][c] = 0.f;

    for (int k0 = 0; k0 < ID; k0 += BK2) {
#pragma unroll
        for (int p = 0; p < 4; ++p) {
            gl16(ap[p], &As[0][0] + (p * 512 + tid) * 8);
            gl16(bp[p], &Bs[0][0] + (p * 512 + tid) * 8);
            ap[p] += BK2; bp[p] += BK2;
        }
        __syncthreads();

#pragma unroll
        for (int kk = 0; kk < 4; ++kk) {
            const int cc = ((kk * 4 + q) ^ ln15) * 8;
            bf16x8 af[2], bf_[4];
#pragma unroll
            for (int i = 0; i < 2; ++i)
                af[i] = *(const bf16x8*)&As[wr * 32 + i * 16 + ln15][cc];
#pragma unroll
            for (int j = 0; j < 4; ++j)
                bf_[j] = *(const bf16x8*)&Bs[wc * 64 + j * 16 + ln15][cc];
#pragma unroll
            for (int i = 0; i < 2; ++i)
#pragma unroll
                for (int j = 0; j < 4; ++j)
                    acc[i][j] = __builtin_amdgcn_mfma_f32_16x16x32_bf16(af[i], bf_[j], acc[i][j], 0, 0, 0);
        }
        __syncthreads();
    }

    // epilogue: weighted plain stores into dense per-row buffer
#pragma unroll
    for (int i = 0; i < 2; ++i) {
#pragma unroll
        for (int reg = 0; reg < 4; ++reg) {
            const int rr = wr * 32 + i * 16 + q * 4 + reg;
            if (r0 + rr < rows) {
                const float w = rww_s[rr];
                float* dst = ybuf + (size_t)(row_base + r0 + rr) * HD + n0 + wc * 64 + ln15;
#pragma unroll
                for (int j = 0; j < 4; ++j)
                    dst[j * 16] = acc[i][j][reg] * w;
            }
        }
    }
}

// --------------------------------------------------------------- combine ----
// wave-per-token: 4 tokens/block, 2048 blocks (fewer blocks, shorter tail).
__global__ __launch_bounds__(256)
void combine_kernel(const float* __restrict__ ybuf, const int* __restrict__ row_pos,
                    float* __restrict__ out)
{
    const int wv = threadIdx.x >> 6, lane = threadIdx.x & 63;
    const int t = blockIdx.x * 4 + wv;
    const int p0 = row_pos[t * 2 + 0], p1 = row_pos[t * 2 + 1];
    const float4* a = (const float4*)(ybuf + (size_t)p0 * HD);
    const float4* b = (const float4*)(ybuf + (size_t)p1 * HD);
    float4* o = (float4*)(out + (size_t)t * HD);
#pragma unroll
    for (int i = 0; i < 4; ++i) {
        const float4 av = a[i * 64 + lane];
        const float4 bv = b[i * 64 + lane];
        float4 ov; ov.x = av.x + bv.x; ov.y = av.y + bv.y;
        ov.z = av.z + bv.z; ov.w = av.w + bv.w;
        o[i * 64 + lane] = ov;
    }
}

// ---------------------------------------------------------------- launch ----
extern "C" void kernel_launch(void* const* d_in, const int* in_sizes, int n_in,
                              void* d_out, int out_size, void* d_ws, size_t ws_size,
                              hipStream_t stream) {
    const float* x   = (const float*)d_in[0];   // (4,2048,1024)
    const float* rw  = (const float*)d_in[1];   // (8,1024)
    const float* w13 = (const float*)d_in[2];   // (8,1024,4096)
    const float* w2  = (const float*)d_in[3];   // (8,2048,1024)
    float* out = (float*)d_out;                 // (4,2048,1024) fp32

    char* ws = (char*)d_ws;
    int*      counts     = (int*)(ws + 0);
    int*      cursor     = (int*)(ws + 64);
    int*      offsets    = (int*)(ws + 128);
    int*      topk_idx   = (int*)(ws + 256);
    float*    topk_w     = (float*)(ws + 256 + 1 * 65536);
    int*      token_list = (int*)(ws + 256 + 2 * 65536);
    float*    row_w      = (float*)(ws + 256 + 3 * 65536);
    int*      row_pos    = (int*)(ws + 256 + 4 * 65536);
    unsigned* map256     = (unsigned*)(ws + 256 + 5 * 65536);
    unsigned* map128     = (unsigned*)(ws + 256 + 6 * 65536);
    const size_t MB = 1024 * 1024;
    bf16_t* xb   = (bf16_t*)(ws + 1 * MB);      // 16 MiB
    bf16_t* hbuf = (bf16_t*)(ws + 17 * MB);     // 64 MiB
    bf16_t* w13b = (bf16_t*)(ws + 81 * MB);     // 64 MiB (dead after gemm1)
    float*  ybuf = (float*)(ws + 81 * MB);      // 64 MiB fp32, ALIASES w13b
                                                // (stream-ordered: gemm1 reads,
                                                //  then gemm2 overwrites)
    bf16_t* w2b  = (bf16_t*)(ws + 145 * MB);    // 32 MiB (ends at 177 MiB)

    hipMemsetAsync(ws, 0, 256, stream);         // counts/cursor/offsets

    dim3 gp1(2 * ID / 64, HD / 64, NEXP);       // w13: K=HD, N=2*ID -> [n][k]
    precast_kernel<<<gp1, 256, 0, stream>>>(w13, w13b, HD, 2 * ID);
    dim3 gp2(HD / 64, ID / 64, NEXP);           // w2: K=ID, N=HD -> [n][k]
    precast_kernel<<<gp2, 256, 0, stream>>>(w2, w2b, ID, HD);

    router_kernel<<<NTOK / 4, 256, 0, stream>>>(x, rw, xb, topk_idx, topk_w);
    count_kernel<<<NTOK / 256, 256, 0, stream>>>(topk_idx, counts);
    scan_kernel<<<1, 64, 0, stream>>>(counts, offsets, cursor, map256, map128);
    scatter_kernel<<<NTOK / 256, 256, 0, stream>>>(topk_idx, topk_w, cursor,
                                                   token_list, row_w, row_pos);

    dim3 g1(ID / 64, MAXT1);                    // 32 x 72 = 2304 blocks (8 | 2304)
    gemm1_kernel<<<g1, 512, 0, stream>>>(xb, w13b, offsets, counts, token_list,
                                         map256, hbuf);
    dim3 g2(HD / 128, MAXT2);                   // 8 x 136 = 1088 blocks (8 | 1088)
    gemm2_kernel<<<g2, 512, 0, stream>>>(hbuf, w2b, offsets, counts, row_w,
                                         map128, ybuf);
    combine_kernel<<<NTOK / 4, 256, 0, stream>>>(ybuf, row_pos, out);
}